// Round 1
// baseline (665.821 us; speedup 1.0000x reference)
//
#include <hip/hip_runtime.h>
#include <math.h>

// EthicalGNN: encoder -> 3x(GAT + BN (+ReLU)) -> mean-pool -> 2 MLP heads.
// Strategy: build CSR (by dst, incl. self-loops) once per launch, then each
// GAT layer = GEMM(xp) + attention-logit dots + per-node gather with online
// softmax (no float atomics in hot path).

#define H4 4  // heads

// ---------------- CSR build ----------------
__global__ void k_init(int* __restrict__ deg, float* __restrict__ gacc, int N) {
  int gid = blockIdx.x * blockDim.x + threadIdx.x;
  if (gid < N) deg[gid] = 1;  // self-loop
  if (gid < 32) gacc[gid] = 0.f;
}

__global__ void k_count(const int* __restrict__ dst, int* __restrict__ deg, int E) {
  int gid = blockIdx.x * blockDim.x + threadIdx.x;
  if (gid < E) atomicAdd(&deg[dst[gid]], 1);
}

// single-block exclusive scan of deg[0..N) -> row_ptr[0..N]
__global__ void k_scan(const int* __restrict__ deg, int* __restrict__ row_ptr, int N) {
  __shared__ int lds[256];
  int tid = threadIdx.x;
  int chunk = (N + 255) / 256;
  int lo = tid * chunk;
  int hi = lo + chunk; if (hi > N) hi = N;
  int s = 0;
  for (int i = lo; i < hi; ++i) s += deg[i];
  lds[tid] = s;
  __syncthreads();
  for (int off = 1; off < 256; off <<= 1) {
    int val = (tid >= off) ? lds[tid - off] : 0;
    __syncthreads();
    lds[tid] += val;
    __syncthreads();
  }
  int run = (tid == 0) ? 0 : lds[tid - 1];
  for (int i = lo; i < hi; ++i) { row_ptr[i] = run; run += deg[i]; }
  if (tid == 255) row_ptr[N] = run;  // total = E + N
}

__global__ void k_selfloop(const int* __restrict__ row_ptr, int* __restrict__ cursor,
                           int* __restrict__ col, int N) {
  int gid = blockIdx.x * blockDim.x + threadIdx.x;
  if (gid < N) {
    int p = row_ptr[gid];
    col[p] = gid;          // self-loop entry
    cursor[gid] = p + 1;
  }
}

__global__ void k_scatter(const int* __restrict__ src, const int* __restrict__ dst,
                          int* __restrict__ cursor, int* __restrict__ col, int E) {
  int gid = blockIdx.x * blockDim.x + threadIdx.x;
  if (gid < E) {
    int p = atomicAdd(&cursor[dst[gid]], 1);
    col[p] = src[gid];
  }
}

// ---------------- encoder: h = x @ enc_W + enc_b  (N,5)@(5,64) ----------------
__global__ void k_enc(const float* __restrict__ x, const float* __restrict__ W,
                      const float* __restrict__ b, float* __restrict__ h, int N) {
  int gid = blockIdx.x * blockDim.x + threadIdx.x;
  if (gid >= N * 64) return;
  int n = gid >> 6, j = gid & 63;
  float acc = b[j];
#pragma unroll
  for (int k = 0; k < 5; ++k) acc += x[n * 5 + k] * W[k * 64 + j];
  h[gid] = acc;
}

// ---------------- xp = h @ W  (N,64)@(64,HC) ----------------
template <int HC>
__global__ void k_gemm(const float* __restrict__ hin, const float* __restrict__ W,
                       float* __restrict__ xp, int N) {
  constexpr int K = 64;
  constexpr int NB = 16;
  __shared__ float hs[NB * K];
  int n0 = blockIdx.x * NB;
  int tid = threadIdx.x;  // 0..HC-1 = output column
  for (int i = tid; i < NB * K; i += HC) {
    int n = n0 + i / K;
    hs[i] = (n < N) ? hin[n0 * K + i] : 0.f;
  }
  __syncthreads();
  float acc[NB];
#pragma unroll
  for (int i = 0; i < NB; ++i) acc[i] = 0.f;
  for (int k = 0; k < K; ++k) {
    float wk = W[k * HC + tid];
#pragma unroll
    for (int i = 0; i < NB; ++i) acc[i] += hs[i * K + k] * wk;
  }
#pragma unroll
  for (int i = 0; i < NB; ++i)
    if (n0 + i < N) xp[(size_t)(n0 + i) * HC + tid] = acc[i];
}

// ---------------- attention logits: al_s/al_d [N,H] ----------------
template <int C>
__global__ void k_al(const float* __restrict__ xp, const float* __restrict__ a_s,
                     const float* __restrict__ a_d, float* __restrict__ als,
                     float* __restrict__ ald, int N) {
  int gid = blockIdx.x * blockDim.x + threadIdx.x;  // n*H + h
  if (gid >= N * H4) return;
  int n = gid / H4, h = gid % H4;
  const float* xpr = xp + (size_t)n * H4 * C + h * C;
  const float* asr = a_s + h * C;
  const float* adr = a_d + h * C;
  float ss = 0.f, sd = 0.f;
#pragma unroll 8
  for (int c = 0; c < C; ++c) {
    float x = xpr[c];
    ss += x * asr[c];
    sd += x * adr[c];
  }
  als[gid] = ss;
  ald[gid] = sd;
}

// ---------------- per-node gather: softmax-weighted aggregate + mean-head
//                  + bias + BN (+ReLU) ----------------
template <int C, bool RELU>
__global__ void k_gather(const float* __restrict__ xp, const float* __restrict__ als,
                         const float* __restrict__ ald, const int* __restrict__ row_ptr,
                         const int* __restrict__ col, const float* __restrict__ bias,
                         const float* __restrict__ g, const float* __restrict__ be,
                         const float* __restrict__ m, const float* __restrict__ v,
                         float* __restrict__ hout) {
  constexpr int HC = H4 * C;
  int n = blockIdx.x;
  int tid = threadIdx.x;        // h*C + c
  int h = tid / C;
  int beg = row_ptr[n], end = row_ptr[n + 1];
  float ald_n = ald[n * H4 + h];

  // pass 1: online softmax stats over in-edges (deg >= 1 via self-loop)
  float mx = -INFINITY, s = 0.f;
  for (int j = beg; j < end; ++j) {
    int src = col[j];
    float e = als[src * H4 + h] + ald_n;
    e = (e > 0.f) ? e : 0.2f * e;  // leaky_relu 0.2
    if (e > mx) {
      s = s * __expf(mx - e) + 1.f;
      mx = e;
    } else {
      s += __expf(e - mx);
    }
  }
  float inv = 1.f / (s + 1e-16f);

  // pass 2: weighted accumulate of xp[src]
  float acc = 0.f;
  for (int j = beg; j < end; ++j) {
    int src = col[j];
    float e = als[src * H4 + h] + ald_n;
    e = (e > 0.f) ? e : 0.2f * e;
    float w = __expf(e - mx) * inv;
    acc += w * xp[(size_t)src * HC + tid];
  }

  __shared__ float lds[HC];
  lds[tid] = acc;
  __syncthreads();
  if (tid < C) {
    float o = 0.f;
#pragma unroll
    for (int hh = 0; hh < H4; ++hh) o += lds[hh * C + tid];
    o = o * (1.f / H4) + bias[tid];
    o = (o - m[tid]) * rsqrtf(v[tid] + 1e-5f) * g[tid] + be[tid];
    if (RELU) o = fmaxf(o, 0.f);
    hout[(size_t)n * C + tid] = o;
  }
}

// ---------------- mean pool over nodes (final h is N x 32) ----------------
__global__ void k_reduce(const float* __restrict__ hfin, float* __restrict__ gacc, int N) {
  __shared__ float lds[256];
  int tid = threadIdx.x;
  int c = tid & 31;
  int rowStart = blockIdx.x * (blockDim.x / 32) + (tid >> 5);
  int rowStride = gridDim.x * (blockDim.x / 32);
  float acc = 0.f;
  for (int n = rowStart; n < N; n += rowStride) acc += hfin[(size_t)n * 32 + c];
  lds[tid] = acc;
  __syncthreads();
  if (tid < 32) {
    float s = 0.f;
#pragma unroll
    for (int i = 0; i < 8; ++i) s += lds[i * 32 + tid];
    atomicAdd(&gacc[tid], s);
  }
}

// ---------------- graph_emb + 2 MLP heads -> out tail ----------------
__global__ void k_heads(const float* __restrict__ gacc,
                        const float* __restrict__ eW1, const float* __restrict__ eb1,
                        const float* __restrict__ eW2, const float* __restrict__ eb2,
                        const float* __restrict__ mW1, const float* __restrict__ mb1,
                        const float* __restrict__ mW2, const float* __restrict__ mb2,
                        float* __restrict__ out, int N) {
  __shared__ float z[32];
  __shared__ float hid[32];  // [0:16) ethics, [16:32) manip
  int tid = threadIdx.x;
  size_t base = (size_t)N * 32;
  if (tid < 32) {
    float zv = gacc[tid] / (float)N;
    z[tid] = zv;
    out[base + tid] = zv;  // graph_emb
  }
  __syncthreads();
  if (tid < 16) {
    float a = eb1[tid], b = mb1[tid];
    for (int k = 0; k < 32; ++k) {
      a += z[k] * eW1[k * 16 + tid];
      b += z[k] * mW1[k * 16 + tid];
    }
    hid[tid] = fmaxf(a, 0.f);
    hid[16 + tid] = fmaxf(b, 0.f);
  }
  __syncthreads();
  if (tid == 0) {
    float a = eb2[0];
    for (int k = 0; k < 16; ++k) a += hid[k] * eW2[k];
    out[base + 32] = 1.f / (1.f + __expf(-a));
  } else if (tid == 1) {
    float a = mb2[0];
    for (int k = 0; k < 16; ++k) a += hid[16 + k] * mW2[k];
    out[base + 33] = 1.f / (1.f + __expf(-a));
  }
}

extern "C" void kernel_launch(void* const* d_in, const int* in_sizes, int n_in,
                              void* d_out, int out_size, void* d_ws, size_t ws_size,
                              hipStream_t stream) {
  const int N = in_sizes[0] / 5;   // x is (N,5)
  const int E = in_sizes[1] / 2;   // edge_index is (2,E)

  const float* x = (const float*)d_in[0];
  const int* ei = (const int*)d_in[1];
  const int* e_src = ei;
  const int* e_dst = ei + E;
  const float* encW = (const float*)d_in[2];
  const float* encb = (const float*)d_in[3];
  // per-layer params at 4 + 8*l: W, as, ad, b, g, be, m, v
  const float* Wl[3]; const float* asl[3]; const float* adl[3]; const float* bl[3];
  const float* gl[3]; const float* bel[3]; const float* ml[3]; const float* vl[3];
  for (int l = 0; l < 3; ++l) {
    const int o = 4 + 8 * l;
    Wl[l]  = (const float*)d_in[o + 0];
    asl[l] = (const float*)d_in[o + 1];
    adl[l] = (const float*)d_in[o + 2];
    bl[l]  = (const float*)d_in[o + 3];
    gl[l]  = (const float*)d_in[o + 4];
    bel[l] = (const float*)d_in[o + 5];
    ml[l]  = (const float*)d_in[o + 6];
    vl[l]  = (const float*)d_in[o + 7];
  }
  const float* eW1 = (const float*)d_in[28];
  const float* eb1 = (const float*)d_in[29];
  const float* eW2 = (const float*)d_in[30];
  const float* eb2 = (const float*)d_in[31];
  const float* mW1 = (const float*)d_in[32];
  const float* mb1 = (const float*)d_in[33];
  const float* mW2 = (const float*)d_in[34];
  const float* mb2 = (const float*)d_in[35];

  float* out = (float*)d_out;

  // workspace layout (floats, then ints)
  float* wf = (float*)d_ws;
  size_t off = 0;
  float* hA   = wf + off; off += (size_t)N * 64;
  float* hB   = wf + off; off += (size_t)N * 64;
  float* xp   = wf + off; off += (size_t)N * 256;
  float* als  = wf + off; off += (size_t)N * 4;
  float* ald  = wf + off; off += (size_t)N * 4;
  float* gacc = wf + off; off += 32;
  int* wi = (int*)(wf + off);
  int* row_ptr = wi;                 // N+1
  int* cursor  = wi + (N + 1);       // N   (doubles as deg before scan)
  int* col     = wi + (2 * N + 1);   // E+N

  const int T = 256;
  const int gN  = (N + T - 1) / T;
  const int gE  = (E + T - 1) / T;
  const int gNE = (N * 64 + T - 1) / T;
  const int gAL = (N * 4 + T - 1) / T;
  const int gGE = (N + 15) / 16;

  // ---- CSR build (deg lives in `cursor`) ----
  k_init<<<gN, T, 0, stream>>>(cursor, gacc, N);
  k_count<<<gE, T, 0, stream>>>(e_dst, cursor, E);
  k_scan<<<1, 256, 0, stream>>>(cursor, row_ptr, N);
  k_selfloop<<<gN, T, 0, stream>>>(row_ptr, cursor, col, N);
  k_scatter<<<gE, T, 0, stream>>>(e_src, e_dst, cursor, col, E);

  // ---- encoder ----
  k_enc<<<gNE, T, 0, stream>>>(x, encW, encb, hA, N);

  // ---- layer 0 (64 -> 64, HC=256) ----
  k_gemm<256><<<gGE, 256, 0, stream>>>(hA, Wl[0], xp, N);
  k_al<64><<<gAL, T, 0, stream>>>(xp, asl[0], adl[0], als, ald, N);
  k_gather<64, true><<<N, 256, 0, stream>>>(xp, als, ald, row_ptr, col,
                                            bl[0], gl[0], bel[0], ml[0], vl[0], hB);

  // ---- layer 1 (64 -> 64, HC=256) ----
  k_gemm<256><<<gGE, 256, 0, stream>>>(hB, Wl[1], xp, N);
  k_al<64><<<gAL, T, 0, stream>>>(xp, asl[1], adl[1], als, ald, N);
  k_gather<64, true><<<N, 256, 0, stream>>>(xp, als, ald, row_ptr, col,
                                            bl[1], gl[1], bel[1], ml[1], vl[1], hA);

  // ---- layer 2 (64 -> 32, HC=128), writes final h straight into d_out ----
  k_gemm<128><<<gGE, 128, 0, stream>>>(hA, Wl[2], xp, N);
  k_al<32><<<gAL, T, 0, stream>>>(xp, asl[2], adl[2], als, ald, N);
  k_gather<32, false><<<N, 128, 0, stream>>>(xp, als, ald, row_ptr, col,
                                             bl[2], gl[2], bel[2], ml[2], vl[2], out);

  // ---- mean pool + heads ----
  k_reduce<<<80, 256, 0, stream>>>(out, gacc, N);
  k_heads<<<1, 64, 0, stream>>>(gacc, eW1, eb1, eW2, eb2, mW1, mb1, mW2, mb2, out, N);
}

// Round 2
// 448.067 us; speedup vs baseline: 1.4860x; 1.4860x over previous
//
#include <hip/hip_runtime.h>
#include <math.h>

// EthicalGNN: encoder -> 3x(GAT + BN (+ReLU)) -> mean-pool -> 2 MLP heads.
// R2: gather restructured — CSR-ordered precomputed exp-logits (k_ee), then a
// single-pass per-node gather (one wave per node, float4 xp loads, shfl head
// reduction, no LDS, no max-subtraction pass).

#define H4 4  // heads

// ---------------- CSR build ----------------
__global__ void k_init(int* __restrict__ deg, float* __restrict__ gacc, int N) {
  int gid = blockIdx.x * blockDim.x + threadIdx.x;
  if (gid < N) deg[gid] = 1;  // self-loop
  if (gid < 32) gacc[gid] = 0.f;
}

__global__ void k_count(const int* __restrict__ dst, int* __restrict__ deg, int E) {
  int gid = blockIdx.x * blockDim.x + threadIdx.x;
  if (gid < E) atomicAdd(&deg[dst[gid]], 1);
}

// single-block exclusive scan of deg[0..N) -> row_ptr[0..N]
__global__ void k_scan(const int* __restrict__ deg, int* __restrict__ row_ptr, int N) {
  __shared__ int lds[256];
  int tid = threadIdx.x;
  int chunk = (N + 255) / 256;
  int lo = tid * chunk;
  int hi = lo + chunk; if (hi > N) hi = N;
  int s = 0;
  for (int i = lo; i < hi; ++i) s += deg[i];
  lds[tid] = s;
  __syncthreads();
  for (int off = 1; off < 256; off <<= 1) {
    int val = (tid >= off) ? lds[tid - off] : 0;
    __syncthreads();
    lds[tid] += val;
    __syncthreads();
  }
  int run = (tid == 0) ? 0 : lds[tid - 1];
  for (int i = lo; i < hi; ++i) { row_ptr[i] = run; run += deg[i]; }
  if (tid == 255) row_ptr[N] = run;  // total = E + N
}

__global__ void k_selfloop(const int* __restrict__ row_ptr, int* __restrict__ cursor,
                           int* __restrict__ col, int* __restrict__ sdst, int N) {
  int gid = blockIdx.x * blockDim.x + threadIdx.x;
  if (gid < N) {
    int p = row_ptr[gid];
    col[p] = gid;          // self-loop entry
    sdst[p] = gid;
    cursor[gid] = p + 1;
  }
}

__global__ void k_scatter(const int* __restrict__ src, const int* __restrict__ dst,
                          int* __restrict__ cursor, int* __restrict__ col,
                          int* __restrict__ sdst, int E) {
  int gid = blockIdx.x * blockDim.x + threadIdx.x;
  if (gid < E) {
    int d = dst[gid];
    int p = atomicAdd(&cursor[d], 1);
    col[p] = src[gid];
    sdst[p] = d;
  }
}

// ---------------- encoder: h = x @ enc_W + enc_b  (N,5)@(5,64) ----------------
__global__ void k_enc(const float* __restrict__ x, const float* __restrict__ W,
                      const float* __restrict__ b, float* __restrict__ h, int N) {
  int gid = blockIdx.x * blockDim.x + threadIdx.x;
  if (gid >= N * 64) return;
  int n = gid >> 6, j = gid & 63;
  float acc = b[j];
#pragma unroll
  for (int k = 0; k < 5; ++k) acc += x[n * 5 + k] * W[k * 64 + j];
  h[gid] = acc;
}

// ---------------- xp = h @ W  (N,64)@(64,HC) ----------------
template <int HC>
__global__ void k_gemm(const float* __restrict__ hin, const float* __restrict__ W,
                       float* __restrict__ xp, int N) {
  constexpr int K = 64;
  constexpr int NB = 16;
  __shared__ float hs[NB * K];
  int n0 = blockIdx.x * NB;
  int tid = threadIdx.x;  // 0..HC-1 = output column
  for (int i = tid; i < NB * K; i += HC) {
    int n = n0 + i / K;
    hs[i] = (n < N) ? hin[n0 * K + i] : 0.f;
  }
  __syncthreads();
  float acc[NB];
#pragma unroll
  for (int i = 0; i < NB; ++i) acc[i] = 0.f;
  for (int k = 0; k < K; ++k) {
    float wk = W[k * HC + tid];
#pragma unroll
    for (int i = 0; i < NB; ++i) acc[i] += hs[i * K + k] * wk;
  }
#pragma unroll
  for (int i = 0; i < NB; ++i)
    if (n0 + i < N) xp[(size_t)(n0 + i) * HC + tid] = acc[i];
}

// ---------------- attention logits: al_s/al_d [N,H] ----------------
template <int C>
__global__ void k_al(const float* __restrict__ xp, const float* __restrict__ a_s,
                     const float* __restrict__ a_d, float* __restrict__ als,
                     float* __restrict__ ald, int N) {
  int gid = blockIdx.x * blockDim.x + threadIdx.x;  // n*H + h
  if (gid >= N * H4) return;
  int n = gid / H4, h = gid % H4;
  const float* xpr = xp + (size_t)n * H4 * C + h * C;
  const float* asr = a_s + h * C;
  const float* adr = a_d + h * C;
  float ss = 0.f, sd = 0.f;
#pragma unroll 8
  for (int c = 0; c < C; ++c) {
    float x = xpr[c];
    ss += x * asr[c];
    sd += x * adr[c];
  }
  als[gid] = ss;
  ald[gid] = sd;
}

// ---------------- per-slot exp(leaky_relu(logit)) in CSR order ----------------
__global__ void k_ee(const int* __restrict__ col, const int* __restrict__ sdst,
                     const float* __restrict__ als, const float* __restrict__ ald,
                     float* __restrict__ ee, int M) {
  int gid = blockIdx.x * blockDim.x + threadIdx.x;  // j*H4 + h
  if (gid >= M * H4) return;
  int j = gid >> 2, h = gid & 3;
  int s = col[j], d = sdst[j];
  float e = als[s * H4 + h] + ald[d * H4 + h];
  e = (e > 0.f) ? e : 0.2f * e;  // leaky_relu 0.2
  ee[gid] = __expf(e);
}

// ---------------- single-pass gather: one wave per node ----------------
// lane = h*16 + c4 ; each lane accumulates VPL = H4*C/64 channels.
// alpha = ee / (sum ee + 1e-16)  (identical to reference's stabilized softmax).
template <int C, bool RELU>
__global__ void k_gather(const float* __restrict__ xp, const float* __restrict__ ee,
                         const int* __restrict__ row_ptr, const int* __restrict__ col,
                         const float* __restrict__ bias, const float* __restrict__ g,
                         const float* __restrict__ be, const float* __restrict__ m,
                         const float* __restrict__ v, float* __restrict__ hout, int N) {
  constexpr int HC = H4 * C;
  constexpr int VPL = HC / 64;  // 4 (C=64) or 2 (C=32)
  int wave = threadIdx.x >> 6;
  int lane = threadIdx.x & 63;
  int n = blockIdx.x * 4 + wave;
  if (n >= N) return;
  int h = lane >> 4;
  int beg = row_ptr[n], end = row_ptr[n + 1];

  float s = 0.f;
  float acc[VPL];
#pragma unroll
  for (int i = 0; i < VPL; ++i) acc[i] = 0.f;

  // software-pipelined: prefetch next (col, ee) while consuming current xp row
  int j = beg;
  int src = col[j];
  float eh = ee[j * H4 + h];
  for (++j; j < end; ++j) {
    int nsrc = col[j];
    float neh = ee[j * H4 + h];
    const float* xr = xp + (size_t)src * HC + lane * VPL;
    s += eh;
#pragma unroll
    for (int i = 0; i < VPL; ++i) acc[i] += eh * xr[i];
    src = nsrc;
    eh = neh;
  }
  {
    const float* xr = xp + (size_t)src * HC + lane * VPL;
    s += eh;
#pragma unroll
    for (int i = 0; i < VPL; ++i) acc[i] += eh * xr[i];
  }

  float inv = 1.f / (s + 1e-16f);
#pragma unroll
  for (int i = 0; i < VPL; ++i) acc[i] *= inv;

  // head sum across lanes (bits 4,5 index the head)
#pragma unroll
  for (int i = 0; i < VPL; ++i) {
    acc[i] += __shfl_xor(acc[i], 16, 64);
    acc[i] += __shfl_xor(acc[i], 32, 64);
  }

  if (lane < 16) {
    int c0 = lane * VPL;
#pragma unroll
    for (int i = 0; i < VPL; ++i) {
      int c = c0 + i;
      float o = acc[i] * (1.f / H4) + bias[c];
      o = (o - m[c]) * rsqrtf(v[c] + 1e-5f) * g[c] + be[c];
      if (RELU) o = fmaxf(o, 0.f);
      hout[(size_t)n * C + c] = o;
    }
  }
}

// ---------------- mean pool over nodes (final h is N x 32) ----------------
__global__ void k_reduce(const float* __restrict__ hfin, float* __restrict__ gacc, int N) {
  __shared__ float lds[256];
  int tid = threadIdx.x;
  int c = tid & 31;
  int rowStart = blockIdx.x * (blockDim.x / 32) + (tid >> 5);
  int rowStride = gridDim.x * (blockDim.x / 32);
  float acc = 0.f;
  for (int n = rowStart; n < N; n += rowStride) acc += hfin[(size_t)n * 32 + c];
  lds[tid] = acc;
  __syncthreads();
  if (tid < 32) {
    float s = 0.f;
#pragma unroll
    for (int i = 0; i < 8; ++i) s += lds[i * 32 + tid];
    atomicAdd(&gacc[tid], s);
  }
}

// ---------------- graph_emb + 2 MLP heads -> out tail ----------------
__global__ void k_heads(const float* __restrict__ gacc,
                        const float* __restrict__ eW1, const float* __restrict__ eb1,
                        const float* __restrict__ eW2, const float* __restrict__ eb2,
                        const float* __restrict__ mW1, const float* __restrict__ mb1,
                        const float* __restrict__ mW2, const float* __restrict__ mb2,
                        float* __restrict__ out, int N) {
  __shared__ float z[32];
  __shared__ float hid[32];  // [0:16) ethics, [16:32) manip
  int tid = threadIdx.x;
  size_t base = (size_t)N * 32;
  if (tid < 32) {
    float zv = gacc[tid] / (float)N;
    z[tid] = zv;
    out[base + tid] = zv;  // graph_emb
  }
  __syncthreads();
  if (tid < 16) {
    float a = eb1[tid], b = mb1[tid];
    for (int k = 0; k < 32; ++k) {
      a += z[k] * eW1[k * 16 + tid];
      b += z[k] * mW1[k * 16 + tid];
    }
    hid[tid] = fmaxf(a, 0.f);
    hid[16 + tid] = fmaxf(b, 0.f);
  }
  __syncthreads();
  if (tid == 0) {
    float a = eb2[0];
    for (int k = 0; k < 16; ++k) a += hid[k] * eW2[k];
    out[base + 32] = 1.f / (1.f + __expf(-a));
  } else if (tid == 1) {
    float a = mb2[0];
    for (int k = 0; k < 16; ++k) a += hid[16 + k] * mW2[k];
    out[base + 33] = 1.f / (1.f + __expf(-a));
  }
}

extern "C" void kernel_launch(void* const* d_in, const int* in_sizes, int n_in,
                              void* d_out, int out_size, void* d_ws, size_t ws_size,
                              hipStream_t stream) {
  const int N = in_sizes[0] / 5;   // x is (N,5)
  const int E = in_sizes[1] / 2;   // edge_index is (2,E)
  const int M = E + N;             // CSR slots incl. self-loops

  const float* x = (const float*)d_in[0];
  const int* ei = (const int*)d_in[1];
  const int* e_src = ei;
  const int* e_dst = ei + E;
  const float* encW = (const float*)d_in[2];
  const float* encb = (const float*)d_in[3];
  // per-layer params at 4 + 8*l: W, as, ad, b, g, be, m, v
  const float* Wl[3]; const float* asl[3]; const float* adl[3]; const float* bl[3];
  const float* gl[3]; const float* bel[3]; const float* ml[3]; const float* vl[3];
  for (int l = 0; l < 3; ++l) {
    const int o = 4 + 8 * l;
    Wl[l]  = (const float*)d_in[o + 0];
    asl[l] = (const float*)d_in[o + 1];
    adl[l] = (const float*)d_in[o + 2];
    bl[l]  = (const float*)d_in[o + 3];
    gl[l]  = (const float*)d_in[o + 4];
    bel[l] = (const float*)d_in[o + 5];
    ml[l]  = (const float*)d_in[o + 6];
    vl[l]  = (const float*)d_in[o + 7];
  }
  const float* eW1 = (const float*)d_in[28];
  const float* eb1 = (const float*)d_in[29];
  const float* eW2 = (const float*)d_in[30];
  const float* eb2 = (const float*)d_in[31];
  const float* mW1 = (const float*)d_in[32];
  const float* mb1 = (const float*)d_in[33];
  const float* mW2 = (const float*)d_in[34];
  const float* mb2 = (const float*)d_in[35];

  float* out = (float*)d_out;

  // workspace layout (floats, then ints)
  float* wf = (float*)d_ws;
  size_t off = 0;
  float* hA   = wf + off; off += (size_t)N * 64;
  float* hB   = wf + off; off += (size_t)N * 64;
  float* xp   = wf + off; off += (size_t)N * 256;
  float* als  = wf + off; off += (size_t)N * 4;
  float* ald  = wf + off; off += (size_t)N * 4;
  float* ee   = wf + off; off += (size_t)M * 4;
  float* gacc = wf + off; off += 32;
  int* wi = (int*)(wf + off);
  int* row_ptr = wi;                 // N+1
  int* cursor  = wi + (N + 1);       // N   (doubles as deg before scan)
  int* col     = wi + (2 * N + 1);   // M
  int* sdst    = col + M;            // M

  const int T = 256;
  const int gN  = (N + T - 1) / T;
  const int gE  = (E + T - 1) / T;
  const int gNE = (N * 64 + T - 1) / T;
  const int gAL = (N * 4 + T - 1) / T;
  const int gEE = (M * 4 + T - 1) / T;
  const int gGE = (N + 15) / 16;
  const int gGA = (N + 3) / 4;       // 4 waves/block, 1 node/wave

  // ---- CSR build (deg lives in `cursor`) ----
  k_init<<<gN, T, 0, stream>>>(cursor, gacc, N);
  k_count<<<gE, T, 0, stream>>>(e_dst, cursor, E);
  k_scan<<<1, 256, 0, stream>>>(cursor, row_ptr, N);
  k_selfloop<<<gN, T, 0, stream>>>(row_ptr, cursor, col, sdst, N);
  k_scatter<<<gE, T, 0, stream>>>(e_src, e_dst, cursor, col, sdst, E);

  // ---- encoder ----
  k_enc<<<gNE, T, 0, stream>>>(x, encW, encb, hA, N);

  // ---- layer 0 (64 -> 64, HC=256) ----
  k_gemm<256><<<gGE, 256, 0, stream>>>(hA, Wl[0], xp, N);
  k_al<64><<<gAL, T, 0, stream>>>(xp, asl[0], adl[0], als, ald, N);
  k_ee<<<gEE, T, 0, stream>>>(col, sdst, als, ald, ee, M);
  k_gather<64, true><<<gGA, 256, 0, stream>>>(xp, ee, row_ptr, col,
                                              bl[0], gl[0], bel[0], ml[0], vl[0], hB, N);

  // ---- layer 1 (64 -> 64, HC=256) ----
  k_gemm<256><<<gGE, 256, 0, stream>>>(hB, Wl[1], xp, N);
  k_al<64><<<gAL, T, 0, stream>>>(xp, asl[1], adl[1], als, ald, N);
  k_ee<<<gEE, T, 0, stream>>>(col, sdst, als, ald, ee, M);
  k_gather<64, true><<<gGA, 256, 0, stream>>>(xp, ee, row_ptr, col,
                                              bl[1], gl[1], bel[1], ml[1], vl[1], hA, N);

  // ---- layer 2 (64 -> 32, HC=128), writes final h straight into d_out ----
  k_gemm<128><<<gGE, 128, 0, stream>>>(hA, Wl[2], xp, N);
  k_al<32><<<gAL, T, 0, stream>>>(xp, asl[2], adl[2], als, ald, N);
  k_ee<<<gEE, T, 0, stream>>>(col, sdst, als, ald, ee, M);
  k_gather<32, false><<<gGA, 256, 0, stream>>>(xp, ee, row_ptr, col,
                                               bl[2], gl[2], bel[2], ml[2], vl[2], out, N);

  // ---- mean pool + heads ----
  k_reduce<<<80, 256, 0, stream>>>(out, gacc, N);
  k_heads<<<1, 64, 0, stream>>>(gacc, eW1, eb1, eW2, eb2, mW1, mb1, mW2, mb2, out, N);
}

// Round 3
// 418.718 us; speedup vs baseline: 1.5901x; 1.0701x over previous
//
#include <hip/hip_runtime.h>
#include <math.h>

// EthicalGNN: encoder -> 3x(GAT + BN (+ReLU)) -> mean-pool -> 2 MLP heads.
// R3: xp stored bf16 (RNE) to halve gather traffic; k_al fused into GEMM
// epilogue (shfl reduce); encoder fused into layer-0 GEMM staging; self-loop
// fused into scan; (src,dst) interleaved int2; gather unrolled 2 edges.

#define H4 4  // heads

static __device__ __forceinline__ unsigned short f2bf(float f) {
  unsigned u = __float_as_uint(f);
  u += 0x7fffu + ((u >> 16) & 1u);  // round-to-nearest-even
  return (unsigned short)(u >> 16);
}

// ---------------- CSR build ----------------
__global__ void k_init(int* __restrict__ deg, float* __restrict__ gacc, int N) {
  int gid = blockIdx.x * blockDim.x + threadIdx.x;
  if (gid < N) deg[gid] = 1;  // self-loop
  if (gid < 32) gacc[gid] = 0.f;
}

__global__ void k_count(const int* __restrict__ dst, int* __restrict__ deg, int E) {
  int gid = blockIdx.x * blockDim.x + threadIdx.x;
  if (gid < E) atomicAdd(&deg[dst[gid]], 1);
}

// single-block exclusive scan of deg -> row_ptr, fused self-loop emission.
// deg lives in `cursor`; after this, cursor[i] = row_ptr[i]+1.
__global__ void k_scan(int* __restrict__ cursor, int* __restrict__ row_ptr,
                       int2* __restrict__ cs, int N) {
  __shared__ int lds[256];
  int tid = threadIdx.x;
  int chunk = (N + 255) / 256;
  int lo = tid * chunk;
  int hi = lo + chunk; if (hi > N) hi = N;
  int s = 0;
  for (int i = lo; i < hi; ++i) s += cursor[i];
  lds[tid] = s;
  __syncthreads();
  for (int off = 1; off < 256; off <<= 1) {
    int val = (tid >= off) ? lds[tid - off] : 0;
    __syncthreads();
    lds[tid] += val;
    __syncthreads();
  }
  int run = (tid == 0) ? 0 : lds[tid - 1];
  for (int i = lo; i < hi; ++i) {
    int d = cursor[i];          // read BEFORE overwriting (same array)
    row_ptr[i] = run;
    cs[run] = make_int2(i, i);  // self-loop slot
    cursor[i] = run + 1;
    run += d;
  }
  if (tid == 255) row_ptr[N] = lds[255];
}

__global__ void k_scatter(const int* __restrict__ src, const int* __restrict__ dst,
                          int* __restrict__ cursor, int2* __restrict__ cs, int E) {
  int gid = blockIdx.x * blockDim.x + threadIdx.x;
  if (gid < E) {
    int d = dst[gid];
    int p = atomicAdd(&cursor[d], 1);
    cs[p] = make_int2(src[gid], d);
  }
}

// ---------------- fused GEMM + attention logits ----------------
// xp(bf16) = hin @ W ; als/ald = rowwise dot with a_s/a_d (shfl reduce).
// ENC: hin is x (N,5), encoder applied during LDS staging.
template <int HC, bool ENC>
__global__ void k_gemm_al(const float* __restrict__ hin,
                          const float* __restrict__ encW, const float* __restrict__ encb,
                          const float* __restrict__ W,
                          const float* __restrict__ a_s, const float* __restrict__ a_d,
                          unsigned short* __restrict__ xpb,
                          float* __restrict__ als, float* __restrict__ ald, int N) {
  constexpr int K = 64, NB = 16, C = HC / H4;
  __shared__ float hs[NB * K];
  int n0 = blockIdx.x * NB;
  int tid = threadIdx.x;  // output column
  if (ENC) {
    for (int idx = tid; idx < NB * K; idx += HC) {
      int i = idx >> 6, j = idx & 63;
      int n = n0 + i;
      float a = 0.f;
      if (n < N) {
        a = encb[j];
#pragma unroll
        for (int k = 0; k < 5; ++k) a += hin[n * 5 + k] * encW[k * 64 + j];
      }
      hs[idx] = a;
    }
  } else {
    for (int idx = tid; idx < NB * K; idx += HC) {
      int n = n0 + (idx >> 6);
      hs[idx] = (n < N) ? hin[(size_t)n0 * K + idx] : 0.f;
    }
  }
  __syncthreads();
  float acc[NB];
#pragma unroll
  for (int i = 0; i < NB; ++i) acc[i] = 0.f;
  for (int k = 0; k < K; k += 4) {
    float w0 = W[(k + 0) * HC + tid];
    float w1 = W[(k + 1) * HC + tid];
    float w2 = W[(k + 2) * HC + tid];
    float w3 = W[(k + 3) * HC + tid];
#pragma unroll
    for (int i = 0; i < NB; ++i) {
      float4 hv = *(const float4*)&hs[i * K + k];
      acc[i] += hv.x * w0 + hv.y * w1 + hv.z * w2 + hv.w * w3;
    }
  }
  // xp in bf16
#pragma unroll
  for (int i = 0; i < NB; ++i) {
    int n = n0 + i;
    if (n < N) xpb[(size_t)n * HC + tid] = f2bf(acc[i]);
  }
  // attention logits: reduce acc[i]*a over the C lanes of each head group
  float as_w = a_s[tid], ad_w = a_d[tid];
  int c = tid & (C - 1);
  int h = tid / C;
#pragma unroll
  for (int i = 0; i < NB; ++i) {
    float vs = acc[i] * as_w, vd = acc[i] * ad_w;
#pragma unroll
    for (int off = C >> 1; off; off >>= 1) {
      vs += __shfl_xor(vs, off, 64);
      vd += __shfl_xor(vd, off, 64);
    }
    int n = n0 + i;
    if (c == 0 && n < N) {
      als[n * H4 + h] = vs;
      ald[n * H4 + h] = vd;
    }
  }
}

// ---------------- per-slot exp(leaky_relu(logit)) in CSR order ----------------
__global__ void k_ee(const int2* __restrict__ cs, const float* __restrict__ als,
                     const float* __restrict__ ald, float* __restrict__ ee, int M) {
  int gid = blockIdx.x * blockDim.x + threadIdx.x;  // j*H4 + h
  if (gid >= M * H4) return;
  int j = gid >> 2, h = gid & 3;
  int2 sd = cs[j];
  float e = als[sd.x * H4 + h] + ald[sd.y * H4 + h];
  e = (e > 0.f) ? e : 0.2f * e;  // leaky_relu 0.2
  ee[gid] = __expf(e);
}

// ---------------- single-pass gather: one wave per node, bf16 xp ----------------
template <int C, bool RELU>
__global__ void k_gather(const unsigned short* __restrict__ xpb, const float* __restrict__ ee,
                         const int* __restrict__ row_ptr, const int2* __restrict__ cs,
                         const float* __restrict__ bias, const float* __restrict__ g,
                         const float* __restrict__ be, const float* __restrict__ m,
                         const float* __restrict__ v, float* __restrict__ hout, int N) {
  constexpr int HC = H4 * C;
  constexpr int VPL = HC / 64;  // 4 (C=64) or 2 (C=32)
  int wave = threadIdx.x >> 6;
  int lane = threadIdx.x & 63;
  int n = blockIdx.x * 4 + wave;
  if (n >= N) return;
  int h = lane >> 4;
  int beg = row_ptr[n], end = row_ptr[n + 1];

  float s = 0.f;
  float acc[VPL];
#pragma unroll
  for (int i = 0; i < VPL; ++i) acc[i] = 0.f;

  int j = beg;
  for (; j + 1 < end; j += 2) {  // two edges in flight
    int s0 = cs[j].x, s1 = cs[j + 1].x;
    float e0 = ee[j * H4 + h], e1 = ee[j * H4 + H4 + h];
    s += e0 + e1;
    if constexpr (VPL == 4) {
      uint2 u0 = *(const uint2*)(xpb + (size_t)s0 * HC + lane * 4);
      uint2 u1 = *(const uint2*)(xpb + (size_t)s1 * HC + lane * 4);
      acc[0] += e0 * __uint_as_float(u0.x << 16) + e1 * __uint_as_float(u1.x << 16);
      acc[1] += e0 * __uint_as_float(u0.x & 0xffff0000u) + e1 * __uint_as_float(u1.x & 0xffff0000u);
      acc[2] += e0 * __uint_as_float(u0.y << 16) + e1 * __uint_as_float(u1.y << 16);
      acc[3] += e0 * __uint_as_float(u0.y & 0xffff0000u) + e1 * __uint_as_float(u1.y & 0xffff0000u);
    } else {
      unsigned u0 = *(const unsigned*)(xpb + (size_t)s0 * HC + lane * 2);
      unsigned u1 = *(const unsigned*)(xpb + (size_t)s1 * HC + lane * 2);
      acc[0] += e0 * __uint_as_float(u0 << 16) + e1 * __uint_as_float(u1 << 16);
      acc[1] += e0 * __uint_as_float(u0 & 0xffff0000u) + e1 * __uint_as_float(u1 & 0xffff0000u);
    }
  }
  if (j < end) {  // tail
    int s0 = cs[j].x;
    float e0 = ee[j * H4 + h];
    s += e0;
    if constexpr (VPL == 4) {
      uint2 u0 = *(const uint2*)(xpb + (size_t)s0 * HC + lane * 4);
      acc[0] += e0 * __uint_as_float(u0.x << 16);
      acc[1] += e0 * __uint_as_float(u0.x & 0xffff0000u);
      acc[2] += e0 * __uint_as_float(u0.y << 16);
      acc[3] += e0 * __uint_as_float(u0.y & 0xffff0000u);
    } else {
      unsigned u0 = *(const unsigned*)(xpb + (size_t)s0 * HC + lane * 2);
      acc[0] += e0 * __uint_as_float(u0 << 16);
      acc[1] += e0 * __uint_as_float(u0 & 0xffff0000u);
    }
  }

  float inv = 1.f / (s + 1e-16f);
#pragma unroll
  for (int i = 0; i < VPL; ++i) {
    acc[i] *= inv;
    acc[i] += __shfl_xor(acc[i], 16, 64);  // head sum (bits 4,5 = head)
    acc[i] += __shfl_xor(acc[i], 32, 64);
  }

  if (lane < 16) {
    int c0 = lane * VPL;
    float o[VPL];
#pragma unroll
    for (int i = 0; i < VPL; ++i) {
      int cc = c0 + i;
      float t = acc[i] * (1.f / H4) + bias[cc];
      t = (t - m[cc]) * rsqrtf(v[cc] + 1e-5f) * g[cc] + be[cc];
      if (RELU) t = fmaxf(t, 0.f);
      o[i] = t;
    }
    if constexpr (VPL == 4)
      *(float4*)&hout[(size_t)n * C + c0] = make_float4(o[0], o[1], o[2], o[3]);
    else
      *(float2*)&hout[(size_t)n * C + c0] = make_float2(o[0], o[1]);
  }
}

// ---------------- mean pool over nodes (final h is N x 32) ----------------
__global__ void k_reduce(const float* __restrict__ hfin, float* __restrict__ gacc, int N) {
  __shared__ float lds[256];
  int tid = threadIdx.x;
  int c = tid & 31;
  int rowStart = blockIdx.x * (blockDim.x / 32) + (tid >> 5);
  int rowStride = gridDim.x * (blockDim.x / 32);
  float acc = 0.f;
  for (int n = rowStart; n < N; n += rowStride) acc += hfin[(size_t)n * 32 + c];
  lds[tid] = acc;
  __syncthreads();
  if (tid < 32) {
    float s = 0.f;
#pragma unroll
    for (int i = 0; i < 8; ++i) s += lds[i * 32 + tid];
    atomicAdd(&gacc[tid], s);
  }
}

// ---------------- graph_emb + 2 MLP heads -> out tail ----------------
__global__ void k_heads(const float* __restrict__ gacc,
                        const float* __restrict__ eW1, const float* __restrict__ eb1,
                        const float* __restrict__ eW2, const float* __restrict__ eb2,
                        const float* __restrict__ mW1, const float* __restrict__ mb1,
                        const float* __restrict__ mW2, const float* __restrict__ mb2,
                        float* __restrict__ out, int N) {
  __shared__ float z[32];
  __shared__ float hid[32];  // [0:16) ethics, [16:32) manip
  int tid = threadIdx.x;
  size_t base = (size_t)N * 32;
  if (tid < 32) {
    float zv = gacc[tid] / (float)N;
    z[tid] = zv;
    out[base + tid] = zv;  // graph_emb
  }
  __syncthreads();
  if (tid < 16) {
    float a = eb1[tid], b = mb1[tid];
    for (int k = 0; k < 32; ++k) {
      a += z[k] * eW1[k * 16 + tid];
      b += z[k] * mW1[k * 16 + tid];
    }
    hid[tid] = fmaxf(a, 0.f);
    hid[16 + tid] = fmaxf(b, 0.f);
  }
  __syncthreads();
  if (tid == 0) {
    float a = eb2[0];
    for (int k = 0; k < 16; ++k) a += hid[k] * eW2[k];
    out[base + 32] = 1.f / (1.f + __expf(-a));
  } else if (tid == 1) {
    float a = mb2[0];
    for (int k = 0; k < 16; ++k) a += hid[16 + k] * mW2[k];
    out[base + 33] = 1.f / (1.f + __expf(-a));
  }
}

extern "C" void kernel_launch(void* const* d_in, const int* in_sizes, int n_in,
                              void* d_out, int out_size, void* d_ws, size_t ws_size,
                              hipStream_t stream) {
  const int N = in_sizes[0] / 5;   // x is (N,5)
  const int E = in_sizes[1] / 2;   // edge_index is (2,E)
  const int M = E + N;             // CSR slots incl. self-loops

  const float* x = (const float*)d_in[0];
  const int* ei = (const int*)d_in[1];
  const int* e_src = ei;
  const int* e_dst = ei + E;
  const float* encW = (const float*)d_in[2];
  const float* encb = (const float*)d_in[3];
  const float* Wl[3]; const float* asl[3]; const float* adl[3]; const float* bl[3];
  const float* gl[3]; const float* bel[3]; const float* ml[3]; const float* vl[3];
  for (int l = 0; l < 3; ++l) {
    const int o = 4 + 8 * l;
    Wl[l]  = (const float*)d_in[o + 0];
    asl[l] = (const float*)d_in[o + 1];
    adl[l] = (const float*)d_in[o + 2];
    bl[l]  = (const float*)d_in[o + 3];
    gl[l]  = (const float*)d_in[o + 4];
    bel[l] = (const float*)d_in[o + 5];
    ml[l]  = (const float*)d_in[o + 6];
    vl[l]  = (const float*)d_in[o + 7];
  }
  const float* eW1 = (const float*)d_in[28];
  const float* eb1 = (const float*)d_in[29];
  const float* eW2 = (const float*)d_in[30];
  const float* eb2 = (const float*)d_in[31];
  const float* mW1 = (const float*)d_in[32];
  const float* mb1 = (const float*)d_in[33];
  const float* mW2 = (const float*)d_in[34];
  const float* mb2 = (const float*)d_in[35];

  float* out = (float*)d_out;

  // workspace layout (floats first, then 8B-aligned int region)
  float* wf = (float*)d_ws;
  size_t off = 0;
  float* hA   = wf + off; off += (size_t)N * 64;
  float* hB   = wf + off; off += (size_t)N * 64;
  unsigned short* xpb = (unsigned short*)(wf + off); off += (size_t)N * 128;  // N*256 bf16
  float* als  = wf + off; off += (size_t)N * 4;
  float* ald  = wf + off; off += (size_t)N * 4;
  float* ee   = wf + off; off += (size_t)M * 4;
  float* gacc = wf + off; off += 32;
  int* wi = (int*)(wf + off);
  int2* cs     = (int2*)wi;          // M slots (src,dst) — 8B aligned
  int* row_ptr = wi + 2 * M;         // N+1
  int* cursor  = wi + 2 * M + N + 1; // N (doubles as deg before scan)

  const int T = 256;
  const int gN  = (N + T - 1) / T;
  const int gE  = (E + T - 1) / T;
  const int gEE = (M * 4 + T - 1) / T;
  const int gGE = (N + 15) / 16;
  const int gGA = (N + 3) / 4;       // 4 waves/block, 1 node/wave

  // ---- CSR build ----
  k_init<<<gN, T, 0, stream>>>(cursor, gacc, N);
  k_count<<<gE, T, 0, stream>>>(e_dst, cursor, E);
  k_scan<<<1, 256, 0, stream>>>(cursor, row_ptr, cs, N);
  k_scatter<<<gE, T, 0, stream>>>(e_src, e_dst, cursor, cs, E);

  // ---- layer 0 (encoder fused; 64 -> 64, HC=256) ----
  k_gemm_al<256, true><<<gGE, 256, 0, stream>>>(x, encW, encb, Wl[0], asl[0], adl[0],
                                                xpb, als, ald, N);
  k_ee<<<gEE, T, 0, stream>>>(cs, als, ald, ee, M);
  k_gather<64, true><<<gGA, 256, 0, stream>>>(xpb, ee, row_ptr, cs,
                                              bl[0], gl[0], bel[0], ml[0], vl[0], hB, N);

  // ---- layer 1 (64 -> 64, HC=256) ----
  k_gemm_al<256, false><<<gGE, 256, 0, stream>>>(hB, encW, encb, Wl[1], asl[1], adl[1],
                                                 xpb, als, ald, N);
  k_ee<<<gEE, T, 0, stream>>>(cs, als, ald, ee, M);
  k_gather<64, true><<<gGA, 256, 0, stream>>>(xpb, ee, row_ptr, cs,
                                              bl[1], gl[1], bel[1], ml[1], vl[1], hA, N);

  // ---- layer 2 (64 -> 32, HC=128), writes final h straight into d_out ----
  k_gemm_al<128, false><<<gGE, 128, 0, stream>>>(hA, encW, encb, Wl[2], asl[2], adl[2],
                                                 xpb, als, ald, N);
  k_ee<<<gEE, T, 0, stream>>>(cs, als, ald, ee, M);
  k_gather<32, false><<<gGA, 256, 0, stream>>>(xpb, ee, row_ptr, cs,
                                               bl[2], gl[2], bel[2], ml[2], vl[2], out, N);

  // ---- mean pool + heads ----
  k_reduce<<<80, 256, 0, stream>>>(out, gacc, N);
  k_heads<<<1, 64, 0, stream>>>(gacc, eW1, eb1, eW2, eb2, mW1, mb1, mW2, mb2, out, N);
}

// Round 4
// 371.321 us; speedup vs baseline: 1.7931x; 1.1276x over previous
//
#include <hip/hip_runtime.h>
#include <math.h>

// EthicalGNN: encoder -> 3x(GAT + BN (+ReLU)) -> mean-pool -> 2 MLP heads.
// R4: serial single-block scan replaced by parallel region allocator
// (wave shfl-scan + one atomicAdd per wave); CSR regions are contiguous per
// node but not globally ordered (nothing depends on global order). k_init
// replaced by memset nodes. Gather blocks 128 threads for finer scheduling.

#define H4 4  // heads

static __device__ __forceinline__ unsigned short f2bf(float f) {
  unsigned u = __float_as_uint(f);
  u += 0x7fffu + ((u >> 16) & 1u);  // round-to-nearest-even
  return (unsigned short)(u >> 16);
}

// ---------------- CSR build ----------------
__global__ void k_count(const int* __restrict__ dst, int* __restrict__ deg, int E) {
  int gid = blockIdx.x * blockDim.x + threadIdx.x;
  if (gid < E) atomicAdd(&deg[dst[gid]], 1);
}

// Parallel region allocator: per-wave inclusive shfl-scan of (deg+1), one
// atomicAdd per wave for the base, then per-lane offsets. Emits self-loop
// slot and initializes the scatter cursor. `deg` lives in `cursor`.
__global__ void k_alloc(int* __restrict__ cursor, int* __restrict__ rbeg,
                        int* __restrict__ rend, int2* __restrict__ cs,
                        int* __restrict__ counter, int N) {
  int gid = blockIdx.x * blockDim.x + threadIdx.x;
  int lane = threadIdx.x & 63;
  int size = (gid < N) ? (cursor[gid] + 1) : 0;  // +1 = self-loop
  int v = size;
#pragma unroll
  for (int off = 1; off < 64; off <<= 1) {
    int t = __shfl_up(v, off, 64);
    if (lane >= off) v += t;
  }
  int tot = __shfl(v, 63, 64);
  int base = 0;
  if (lane == 63) base = atomicAdd(counter, tot);
  base = __shfl(base, 63, 64);
  if (gid < N) {
    int p = base + v - size;  // exclusive prefix
    rbeg[gid] = p;
    rend[gid] = p + size;
    cs[p] = make_int2(gid, gid);  // self-loop slot
    cursor[gid] = p + 1;
  }
}

__global__ void k_scatter(const int* __restrict__ src, const int* __restrict__ dst,
                          int* __restrict__ cursor, int2* __restrict__ cs, int E) {
  int gid = blockIdx.x * blockDim.x + threadIdx.x;
  if (gid < E) {
    int d = dst[gid];
    int p = atomicAdd(&cursor[d], 1);
    cs[p] = make_int2(src[gid], d);
  }
}

// ---------------- fused GEMM + attention logits ----------------
// xp(bf16) = hin @ W ; als/ald = rowwise dot with a_s/a_d (shfl reduce).
// ENC: hin is x (N,5), encoder applied during LDS staging.
template <int HC, bool ENC>
__global__ void k_gemm_al(const float* __restrict__ hin,
                          const float* __restrict__ encW, const float* __restrict__ encb,
                          const float* __restrict__ W,
                          const float* __restrict__ a_s, const float* __restrict__ a_d,
                          unsigned short* __restrict__ xpb,
                          float* __restrict__ als, float* __restrict__ ald, int N) {
  constexpr int K = 64, NB = 16, C = HC / H4;
  __shared__ float hs[NB * K];
  int n0 = blockIdx.x * NB;
  int tid = threadIdx.x;  // output column
  if (ENC) {
    for (int idx = tid; idx < NB * K; idx += HC) {
      int i = idx >> 6, j = idx & 63;
      int n = n0 + i;
      float a = 0.f;
      if (n < N) {
        a = encb[j];
#pragma unroll
        for (int k = 0; k < 5; ++k) a += hin[n * 5 + k] * encW[k * 64 + j];
      }
      hs[idx] = a;
    }
  } else {
    for (int idx = tid; idx < NB * K; idx += HC) {
      int n = n0 + (idx >> 6);
      hs[idx] = (n < N) ? hin[(size_t)n0 * K + idx] : 0.f;
    }
  }
  __syncthreads();
  float acc[NB];
#pragma unroll
  for (int i = 0; i < NB; ++i) acc[i] = 0.f;
  for (int k = 0; k < K; k += 4) {
    float w0 = W[(k + 0) * HC + tid];
    float w1 = W[(k + 1) * HC + tid];
    float w2 = W[(k + 2) * HC + tid];
    float w3 = W[(k + 3) * HC + tid];
#pragma unroll
    for (int i = 0; i < NB; ++i) {
      float4 hv = *(const float4*)&hs[i * K + k];
      acc[i] += hv.x * w0 + hv.y * w1 + hv.z * w2 + hv.w * w3;
    }
  }
#pragma unroll
  for (int i = 0; i < NB; ++i) {
    int n = n0 + i;
    if (n < N) xpb[(size_t)n * HC + tid] = f2bf(acc[i]);
  }
  float as_w = a_s[tid], ad_w = a_d[tid];
  int c = tid & (C - 1);
  int h = tid / C;
#pragma unroll
  for (int i = 0; i < NB; ++i) {
    float vs = acc[i] * as_w, vd = acc[i] * ad_w;
#pragma unroll
    for (int off = C >> 1; off; off >>= 1) {
      vs += __shfl_xor(vs, off, 64);
      vd += __shfl_xor(vd, off, 64);
    }
    int n = n0 + i;
    if (c == 0 && n < N) {
      als[n * H4 + h] = vs;
      ald[n * H4 + h] = vd;
    }
  }
}

// ---------------- per-slot exp(leaky_relu(logit)) in CSR order ----------------
__global__ void k_ee(const int2* __restrict__ cs, const float* __restrict__ als,
                     const float* __restrict__ ald, float* __restrict__ ee, int M) {
  int gid = blockIdx.x * blockDim.x + threadIdx.x;  // j*H4 + h
  if (gid >= M * H4) return;
  int j = gid >> 2, h = gid & 3;
  int2 sd = cs[j];
  float e = als[sd.x * H4 + h] + ald[sd.y * H4 + h];
  e = (e > 0.f) ? e : 0.2f * e;  // leaky_relu 0.2
  ee[gid] = __expf(e);
}

// ---------------- single-pass gather: one wave per node, bf16 xp ----------------
template <int C, bool RELU>
__global__ void k_gather(const unsigned short* __restrict__ xpb, const float* __restrict__ ee,
                         const int* __restrict__ rbeg, const int* __restrict__ rend,
                         const int2* __restrict__ cs,
                         const float* __restrict__ bias, const float* __restrict__ g,
                         const float* __restrict__ be, const float* __restrict__ m,
                         const float* __restrict__ v, float* __restrict__ hout, int N) {
  constexpr int HC = H4 * C;
  constexpr int VPL = HC / 64;  // 4 (C=64) or 2 (C=32)
  int wave = threadIdx.x >> 6;
  int lane = threadIdx.x & 63;
  int n = blockIdx.x * 2 + wave;  // 128-thread blocks, 2 waves
  if (n >= N) return;
  int h = lane >> 4;
  int beg = rbeg[n], end = rend[n];

  float s = 0.f;
  float acc[VPL];
#pragma unroll
  for (int i = 0; i < VPL; ++i) acc[i] = 0.f;

  int j = beg;
  for (; j + 1 < end; j += 2) {  // two edges in flight
    int s0 = cs[j].x, s1 = cs[j + 1].x;
    float e0 = ee[j * H4 + h], e1 = ee[j * H4 + H4 + h];
    s += e0 + e1;
    if constexpr (VPL == 4) {
      uint2 u0 = *(const uint2*)(xpb + (size_t)s0 * HC + lane * 4);
      uint2 u1 = *(const uint2*)(xpb + (size_t)s1 * HC + lane * 4);
      acc[0] += e0 * __uint_as_float(u0.x << 16) + e1 * __uint_as_float(u1.x << 16);
      acc[1] += e0 * __uint_as_float(u0.x & 0xffff0000u) + e1 * __uint_as_float(u1.x & 0xffff0000u);
      acc[2] += e0 * __uint_as_float(u0.y << 16) + e1 * __uint_as_float(u1.y << 16);
      acc[3] += e0 * __uint_as_float(u0.y & 0xffff0000u) + e1 * __uint_as_float(u1.y & 0xffff0000u);
    } else {
      unsigned u0 = *(const unsigned*)(xpb + (size_t)s0 * HC + lane * 2);
      unsigned u1 = *(const unsigned*)(xpb + (size_t)s1 * HC + lane * 2);
      acc[0] += e0 * __uint_as_float(u0 << 16) + e1 * __uint_as_float(u1 << 16);
      acc[1] += e0 * __uint_as_float(u0 & 0xffff0000u) + e1 * __uint_as_float(u1 & 0xffff0000u);
    }
  }
  if (j < end) {  // tail
    int s0 = cs[j].x;
    float e0 = ee[j * H4 + h];
    s += e0;
    if constexpr (VPL == 4) {
      uint2 u0 = *(const uint2*)(xpb + (size_t)s0 * HC + lane * 4);
      acc[0] += e0 * __uint_as_float(u0.x << 16);
      acc[1] += e0 * __uint_as_float(u0.x & 0xffff0000u);
      acc[2] += e0 * __uint_as_float(u0.y << 16);
      acc[3] += e0 * __uint_as_float(u0.y & 0xffff0000u);
    } else {
      unsigned u0 = *(const unsigned*)(xpb + (size_t)s0 * HC + lane * 2);
      acc[0] += e0 * __uint_as_float(u0 << 16);
      acc[1] += e0 * __uint_as_float(u0 & 0xffff0000u);
    }
  }

  float inv = 1.f / (s + 1e-16f);
#pragma unroll
  for (int i = 0; i < VPL; ++i) {
    acc[i] *= inv;
    acc[i] += __shfl_xor(acc[i], 16, 64);  // head sum (bits 4,5 = head)
    acc[i] += __shfl_xor(acc[i], 32, 64);
  }

  if (lane < 16) {
    int c0 = lane * VPL;
    float o[VPL];
#pragma unroll
    for (int i = 0; i < VPL; ++i) {
      int cc = c0 + i;
      float t = acc[i] * (1.f / H4) + bias[cc];
      t = (t - m[cc]) * rsqrtf(v[cc] + 1e-5f) * g[cc] + be[cc];
      if (RELU) t = fmaxf(t, 0.f);
      o[i] = t;
    }
    if constexpr (VPL == 4)
      *(float4*)&hout[(size_t)n * C + c0] = make_float4(o[0], o[1], o[2], o[3]);
    else
      *(float2*)&hout[(size_t)n * C + c0] = make_float2(o[0], o[1]);
  }
}

// ---------------- mean pool over nodes (final h is N x 32) ----------------
__global__ void k_reduce(const float* __restrict__ hfin, float* __restrict__ gacc, int N) {
  __shared__ float lds[256];
  int tid = threadIdx.x;
  int c = tid & 31;
  int rowStart = blockIdx.x * (blockDim.x / 32) + (tid >> 5);
  int rowStride = gridDim.x * (blockDim.x / 32);
  float acc = 0.f;
  for (int n = rowStart; n < N; n += rowStride) acc += hfin[(size_t)n * 32 + c];
  lds[tid] = acc;
  __syncthreads();
  if (tid < 32) {
    float s = 0.f;
#pragma unroll
    for (int i = 0; i < 8; ++i) s += lds[i * 32 + tid];
    atomicAdd(&gacc[tid], s);
  }
}

// ---------------- graph_emb + 2 MLP heads -> out tail ----------------
__global__ void k_heads(const float* __restrict__ gacc,
                        const float* __restrict__ eW1, const float* __restrict__ eb1,
                        const float* __restrict__ eW2, const float* __restrict__ eb2,
                        const float* __restrict__ mW1, const float* __restrict__ mb1,
                        const float* __restrict__ mW2, const float* __restrict__ mb2,
                        float* __restrict__ out, int N) {
  __shared__ float z[32];
  __shared__ float hid[32];  // [0:16) ethics, [16:32) manip
  int tid = threadIdx.x;
  size_t base = (size_t)N * 32;
  if (tid < 32) {
    float zv = gacc[tid] / (float)N;
    z[tid] = zv;
    out[base + tid] = zv;  // graph_emb
  }
  __syncthreads();
  if (tid < 16) {
    float a = eb1[tid], b = mb1[tid];
    for (int k = 0; k < 32; ++k) {
      a += z[k] * eW1[k * 16 + tid];
      b += z[k] * mW1[k * 16 + tid];
    }
    hid[tid] = fmaxf(a, 0.f);
    hid[16 + tid] = fmaxf(b, 0.f);
  }
  __syncthreads();
  if (tid == 0) {
    float a = eb2[0];
    for (int k = 0; k < 16; ++k) a += hid[k] * eW2[k];
    out[base + 32] = 1.f / (1.f + __expf(-a));
  } else if (tid == 1) {
    float a = mb2[0];
    for (int k = 0; k < 16; ++k) a += hid[16 + k] * mW2[k];
    out[base + 33] = 1.f / (1.f + __expf(-a));
  }
}

extern "C" void kernel_launch(void* const* d_in, const int* in_sizes, int n_in,
                              void* d_out, int out_size, void* d_ws, size_t ws_size,
                              hipStream_t stream) {
  const int N = in_sizes[0] / 5;   // x is (N,5)
  const int E = in_sizes[1] / 2;   // edge_index is (2,E)
  const int M = E + N;             // CSR slots incl. self-loops

  const float* x = (const float*)d_in[0];
  const int* ei = (const int*)d_in[1];
  const int* e_src = ei;
  const int* e_dst = ei + E;
  const float* encW = (const float*)d_in[2];
  const float* encb = (const float*)d_in[3];
  const float* Wl[3]; const float* asl[3]; const float* adl[3]; const float* bl[3];
  const float* gl[3]; const float* bel[3]; const float* ml[3]; const float* vl[3];
  for (int l = 0; l < 3; ++l) {
    const int o = 4 + 8 * l;
    Wl[l]  = (const float*)d_in[o + 0];
    asl[l] = (const float*)d_in[o + 1];
    adl[l] = (const float*)d_in[o + 2];
    bl[l]  = (const float*)d_in[o + 3];
    gl[l]  = (const float*)d_in[o + 4];
    bel[l] = (const float*)d_in[o + 5];
    ml[l]  = (const float*)d_in[o + 6];
    vl[l]  = (const float*)d_in[o + 7];
  }
  const float* eW1 = (const float*)d_in[28];
  const float* eb1 = (const float*)d_in[29];
  const float* eW2 = (const float*)d_in[30];
  const float* eb2 = (const float*)d_in[31];
  const float* mW1 = (const float*)d_in[32];
  const float* mb1 = (const float*)d_in[33];
  const float* mW2 = (const float*)d_in[34];
  const float* mb2 = (const float*)d_in[35];

  float* out = (float*)d_out;

  // workspace layout (floats first, then 8B-aligned int region)
  float* wf = (float*)d_ws;
  size_t off = 0;
  float* hA   = wf + off; off += (size_t)N * 64;
  float* hB   = wf + off; off += (size_t)N * 64;
  unsigned short* xpb = (unsigned short*)(wf + off); off += (size_t)N * 128;  // N*256 bf16
  float* als  = wf + off; off += (size_t)N * 4;
  float* ald  = wf + off; off += (size_t)N * 4;
  float* ee   = wf + off; off += (size_t)M * 4;
  float* gacc = wf + off; off += 32;
  int* wi = (int*)(wf + off);
  int2* cs     = (int2*)wi;              // M slots (src,dst) — 8B aligned
  int* rbeg    = wi + 2 * M;             // N
  int* rend    = rbeg + N;               // N
  int* cursor  = rend + N;               // N (deg before alloc)
  int* counter = cursor + N;             // 1

  const int T = 256;
  const int gN  = (N + T - 1) / T;
  const int gE  = (E + T - 1) / T;
  const int gEE = (M * 4 + T - 1) / T;
  const int gGE = (N + 15) / 16;
  const int gGA = (N + 1) / 2;       // 128-thread blocks, 2 waves, 1 node/wave

  // ---- CSR build ----
  hipMemsetAsync(cursor, 0, (size_t)(N + 1) * sizeof(int), stream);  // deg + counter
  hipMemsetAsync(gacc, 0, 32 * sizeof(float), stream);
  k_count<<<gE, T, 0, stream>>>(e_dst, cursor, E);
  k_alloc<<<gN, T, 0, stream>>>(cursor, rbeg, rend, cs, counter, N);
  k_scatter<<<gE, T, 0, stream>>>(e_src, e_dst, cursor, cs, E);

  // ---- layer 0 (encoder fused; 64 -> 64, HC=256) ----
  k_gemm_al<256, true><<<gGE, 256, 0, stream>>>(x, encW, encb, Wl[0], asl[0], adl[0],
                                                xpb, als, ald, N);
  k_ee<<<gEE, T, 0, stream>>>(cs, als, ald, ee, M);
  k_gather<64, true><<<gGA, 128, 0, stream>>>(xpb, ee, rbeg, rend, cs,
                                              bl[0], gl[0], bel[0], ml[0], vl[0], hB, N);

  // ---- layer 1 (64 -> 64, HC=256) ----
  k_gemm_al<256, false><<<gGE, 256, 0, stream>>>(hB, encW, encb, Wl[1], asl[1], adl[1],
                                                 xpb, als, ald, N);
  k_ee<<<gEE, T, 0, stream>>>(cs, als, ald, ee, M);
  k_gather<64, true><<<gGA, 128, 0, stream>>>(xpb, ee, rbeg, rend, cs,
                                              bl[1], gl[1], bel[1], ml[1], vl[1], hA, N);

  // ---- layer 2 (64 -> 32, HC=128), writes final h straight into d_out ----
  k_gemm_al<128, false><<<gGE, 128, 0, stream>>>(hA, encW, encb, Wl[2], asl[2], adl[2],
                                                 xpb, als, ald, N);
  k_ee<<<gEE, T, 0, stream>>>(cs, als, ald, ee, M);
  k_gather<32, false><<<gGA, 128, 0, stream>>>(xpb, ee, rbeg, rend, cs,
                                               bl[2], gl[2], bel[2], ml[2], vl[2], out, N);

  // ---- mean pool + heads ----
  k_reduce<<<80, 256, 0, stream>>>(out, gacc, N);
  k_heads<<<1, 64, 0, stream>>>(gacc, eW1, eb1, eW2, eb2, mW1, mb1, mW2, mb2, out, N);
}

// Round 5
// 355.794 us; speedup vs baseline: 1.8714x; 1.0436x over previous
//
#include <hip/hip_runtime.h>
#include <math.h>

// EthicalGNN: encoder -> 3x(GAT + BN (+ReLU)) -> mean-pool -> 2 MLP heads.
// R5: k_ee fused into k_gather (exp/leaky_relu computed in the gather loop
// from als[src]+ald[n]); CSR stores only col (4B/edge, sdst dropped); gacc
// zeroed in k_alloc (one memset node). 13 graph nodes total.

#define H4 4  // heads

static __device__ __forceinline__ unsigned short f2bf(float f) {
  unsigned u = __float_as_uint(f);
  u += 0x7fffu + ((u >> 16) & 1u);  // round-to-nearest-even
  return (unsigned short)(u >> 16);
}

// ---------------- CSR build ----------------
__global__ void k_count(const int* __restrict__ dst, int* __restrict__ deg, int E) {
  int gid = blockIdx.x * blockDim.x + threadIdx.x;
  if (gid < E) atomicAdd(&deg[dst[gid]], 1);
}

// Parallel region allocator: per-wave inclusive shfl-scan of (deg+1), one
// atomicAdd per wave for the base, then per-lane offsets. Emits self-loop
// slot, initializes scatter cursor, zeroes gacc. `deg` lives in `cursor`.
__global__ void k_alloc(int* __restrict__ cursor, int* __restrict__ rbeg,
                        int* __restrict__ rend, int* __restrict__ col,
                        int* __restrict__ counter, float* __restrict__ gacc, int N) {
  int gid = blockIdx.x * blockDim.x + threadIdx.x;
  int lane = threadIdx.x & 63;
  if (gid < 32) gacc[gid] = 0.f;  // block 0 runs before k_reduce in-stream
  int size = (gid < N) ? (cursor[gid] + 1) : 0;  // +1 = self-loop
  int v = size;
#pragma unroll
  for (int off = 1; off < 64; off <<= 1) {
    int t = __shfl_up(v, off, 64);
    if (lane >= off) v += t;
  }
  int tot = __shfl(v, 63, 64);
  int base = 0;
  if (lane == 63) base = atomicAdd(counter, tot);
  base = __shfl(base, 63, 64);
  if (gid < N) {
    int p = base + v - size;  // exclusive prefix
    rbeg[gid] = p;
    rend[gid] = p + size;
    col[p] = gid;             // self-loop slot
    cursor[gid] = p + 1;
  }
}

__global__ void k_scatter(const int* __restrict__ src, const int* __restrict__ dst,
                          int* __restrict__ cursor, int* __restrict__ col, int E) {
  int gid = blockIdx.x * blockDim.x + threadIdx.x;
  if (gid < E) {
    int p = atomicAdd(&cursor[dst[gid]], 1);
    col[p] = src[gid];
  }
}

// ---------------- fused GEMM + attention logits ----------------
// xp(bf16) = hin @ W ; als/ald = rowwise dot with a_s/a_d (shfl reduce).
// ENC: hin is x (N,5), encoder applied during LDS staging.
template <int HC, bool ENC>
__global__ void k_gemm_al(const float* __restrict__ hin,
                          const float* __restrict__ encW, const float* __restrict__ encb,
                          const float* __restrict__ W,
                          const float* __restrict__ a_s, const float* __restrict__ a_d,
                          unsigned short* __restrict__ xpb,
                          float* __restrict__ als, float* __restrict__ ald, int N) {
  constexpr int K = 64, NB = 16, C = HC / H4;
  __shared__ float hs[NB * K];
  int n0 = blockIdx.x * NB;
  int tid = threadIdx.x;  // output column
  if (ENC) {
    for (int idx = tid; idx < NB * K; idx += HC) {
      int i = idx >> 6, j = idx & 63;
      int n = n0 + i;
      float a = 0.f;
      if (n < N) {
        a = encb[j];
#pragma unroll
        for (int k = 0; k < 5; ++k) a += hin[n * 5 + k] * encW[k * 64 + j];
      }
      hs[idx] = a;
    }
  } else {
    for (int idx = tid; idx < NB * K; idx += HC) {
      int n = n0 + (idx >> 6);
      hs[idx] = (n < N) ? hin[(size_t)n0 * K + idx] : 0.f;
    }
  }
  __syncthreads();
  float acc[NB];
#pragma unroll
  for (int i = 0; i < NB; ++i) acc[i] = 0.f;
  for (int k = 0; k < K; k += 4) {
    float w0 = W[(k + 0) * HC + tid];
    float w1 = W[(k + 1) * HC + tid];
    float w2 = W[(k + 2) * HC + tid];
    float w3 = W[(k + 3) * HC + tid];
#pragma unroll
    for (int i = 0; i < NB; ++i) {
      float4 hv = *(const float4*)&hs[i * K + k];
      acc[i] += hv.x * w0 + hv.y * w1 + hv.z * w2 + hv.w * w3;
    }
  }
#pragma unroll
  for (int i = 0; i < NB; ++i) {
    int n = n0 + i;
    if (n < N) xpb[(size_t)n * HC + tid] = f2bf(acc[i]);
  }
  float as_w = a_s[tid], ad_w = a_d[tid];
  int c = tid & (C - 1);
  int h = tid / C;
#pragma unroll
  for (int i = 0; i < NB; ++i) {
    float vs = acc[i] * as_w, vd = acc[i] * ad_w;
#pragma unroll
    for (int off = C >> 1; off; off >>= 1) {
      vs += __shfl_xor(vs, off, 64);
      vd += __shfl_xor(vd, off, 64);
    }
    int n = n0 + i;
    if (c == 0 && n < N) {
      als[n * H4 + h] = vs;
      ald[n * H4 + h] = vd;
    }
  }
}

// ---------------- single-pass gather with fused softmax logits ----------------
// lane = h*16 + c4. alpha = exp(lrelu(als[src]+ald[n])) / (sum + 1e-16).
template <int C, bool RELU>
__global__ void k_gather(const unsigned short* __restrict__ xpb,
                         const float* __restrict__ als, const float* __restrict__ ald,
                         const int* __restrict__ rbeg, const int* __restrict__ rend,
                         const int* __restrict__ col,
                         const float* __restrict__ bias, const float* __restrict__ g,
                         const float* __restrict__ be, const float* __restrict__ m,
                         const float* __restrict__ v, float* __restrict__ hout, int N) {
  constexpr int HC = H4 * C;
  constexpr int VPL = HC / 64;  // 4 (C=64) or 2 (C=32)
  int wave = threadIdx.x >> 6;
  int lane = threadIdx.x & 63;
  int n = blockIdx.x * 2 + wave;  // 128-thread blocks, 2 waves
  if (n >= N) return;
  int h = lane >> 4;
  float aldn = ald[n * H4 + h];
  int beg = rbeg[n], end = rend[n];

  float s = 0.f;
  float acc[VPL];
#pragma unroll
  for (int i = 0; i < VPL; ++i) acc[i] = 0.f;

  int j = beg;
  for (; j + 1 < end; j += 2) {  // two edges in flight
    int s0 = col[j], s1 = col[j + 1];
    float a0 = als[s0 * H4 + h], a1 = als[s1 * H4 + h];
    float e0 = a0 + aldn; e0 = (e0 > 0.f) ? e0 : 0.2f * e0; e0 = __expf(e0);
    float e1 = a1 + aldn; e1 = (e1 > 0.f) ? e1 : 0.2f * e1; e1 = __expf(e1);
    s += e0 + e1;
    if constexpr (VPL == 4) {
      uint2 u0 = *(const uint2*)(xpb + (size_t)s0 * HC + lane * 4);
      uint2 u1 = *(const uint2*)(xpb + (size_t)s1 * HC + lane * 4);
      acc[0] += e0 * __uint_as_float(u0.x << 16) + e1 * __uint_as_float(u1.x << 16);
      acc[1] += e0 * __uint_as_float(u0.x & 0xffff0000u) + e1 * __uint_as_float(u1.x & 0xffff0000u);
      acc[2] += e0 * __uint_as_float(u0.y << 16) + e1 * __uint_as_float(u1.y << 16);
      acc[3] += e0 * __uint_as_float(u0.y & 0xffff0000u) + e1 * __uint_as_float(u1.y & 0xffff0000u);
    } else {
      unsigned u0 = *(const unsigned*)(xpb + (size_t)s0 * HC + lane * 2);
      unsigned u1 = *(const unsigned*)(xpb + (size_t)s1 * HC + lane * 2);
      acc[0] += e0 * __uint_as_float(u0 << 16) + e1 * __uint_as_float(u1 << 16);
      acc[1] += e0 * __uint_as_float(u0 & 0xffff0000u) + e1 * __uint_as_float(u1 & 0xffff0000u);
    }
  }
  if (j < end) {  // tail
    int s0 = col[j];
    float a0 = als[s0 * H4 + h];
    float e0 = a0 + aldn; e0 = (e0 > 0.f) ? e0 : 0.2f * e0; e0 = __expf(e0);
    s += e0;
    if constexpr (VPL == 4) {
      uint2 u0 = *(const uint2*)(xpb + (size_t)s0 * HC + lane * 4);
      acc[0] += e0 * __uint_as_float(u0.x << 16);
      acc[1] += e0 * __uint_as_float(u0.x & 0xffff0000u);
      acc[2] += e0 * __uint_as_float(u0.y << 16);
      acc[3] += e0 * __uint_as_float(u0.y & 0xffff0000u);
    } else {
      unsigned u0 = *(const unsigned*)(xpb + (size_t)s0 * HC + lane * 2);
      acc[0] += e0 * __uint_as_float(u0 << 16);
      acc[1] += e0 * __uint_as_float(u0 & 0xffff0000u);
    }
  }

  float inv = 1.f / (s + 1e-16f);
#pragma unroll
  for (int i = 0; i < VPL; ++i) {
    acc[i] *= inv;
    acc[i] += __shfl_xor(acc[i], 16, 64);  // head sum (bits 4,5 = head)
    acc[i] += __shfl_xor(acc[i], 32, 64);
  }

  if (lane < 16) {
    int c0 = lane * VPL;
    float o[VPL];
#pragma unroll
    for (int i = 0; i < VPL; ++i) {
      int cc = c0 + i;
      float t = acc[i] * (1.f / H4) + bias[cc];
      t = (t - m[cc]) * rsqrtf(v[cc] + 1e-5f) * g[cc] + be[cc];
      if (RELU) t = fmaxf(t, 0.f);
      o[i] = t;
    }
    if constexpr (VPL == 4)
      *(float4*)&hout[(size_t)n * C + c0] = make_float4(o[0], o[1], o[2], o[3]);
    else
      *(float2*)&hout[(size_t)n * C + c0] = make_float2(o[0], o[1]);
  }
}

// ---------------- mean pool over nodes (final h is N x 32) ----------------
__global__ void k_reduce(const float* __restrict__ hfin, float* __restrict__ gacc, int N) {
  __shared__ float lds[256];
  int tid = threadIdx.x;
  int c = tid & 31;
  int rowStart = blockIdx.x * (blockDim.x / 32) + (tid >> 5);
  int rowStride = gridDim.x * (blockDim.x / 32);
  float acc = 0.f;
  for (int n = rowStart; n < N; n += rowStride) acc += hfin[(size_t)n * 32 + c];
  lds[tid] = acc;
  __syncthreads();
  if (tid < 32) {
    float s = 0.f;
#pragma unroll
    for (int i = 0; i < 8; ++i) s += lds[i * 32 + tid];
    atomicAdd(&gacc[tid], s);
  }
}

// ---------------- graph_emb + 2 MLP heads -> out tail ----------------
__global__ void k_heads(const float* __restrict__ gacc,
                        const float* __restrict__ eW1, const float* __restrict__ eb1,
                        const float* __restrict__ eW2, const float* __restrict__ eb2,
                        const float* __restrict__ mW1, const float* __restrict__ mb1,
                        const float* __restrict__ mW2, const float* __restrict__ mb2,
                        float* __restrict__ out, int N) {
  __shared__ float z[32];
  __shared__ float hid[32];  // [0:16) ethics, [16:32) manip
  int tid = threadIdx.x;
  size_t base = (size_t)N * 32;
  if (tid < 32) {
    float zv = gacc[tid] / (float)N;
    z[tid] = zv;
    out[base + tid] = zv;  // graph_emb
  }
  __syncthreads();
  if (tid < 16) {
    float a = eb1[tid], b = mb1[tid];
    for (int k = 0; k < 32; ++k) {
      a += z[k] * eW1[k * 16 + tid];
      b += z[k] * mW1[k * 16 + tid];
    }
    hid[tid] = fmaxf(a, 0.f);
    hid[16 + tid] = fmaxf(b, 0.f);
  }
  __syncthreads();
  if (tid == 0) {
    float a = eb2[0];
    for (int k = 0; k < 16; ++k) a += hid[k] * eW2[k];
    out[base + 32] = 1.f / (1.f + __expf(-a));
  } else if (tid == 1) {
    float a = mb2[0];
    for (int k = 0; k < 16; ++k) a += hid[16 + k] * mW2[k];
    out[base + 33] = 1.f / (1.f + __expf(-a));
  }
}

extern "C" void kernel_launch(void* const* d_in, const int* in_sizes, int n_in,
                              void* d_out, int out_size, void* d_ws, size_t ws_size,
                              hipStream_t stream) {
  const int N = in_sizes[0] / 5;   // x is (N,5)
  const int E = in_sizes[1] / 2;   // edge_index is (2,E)
  const int M = E + N;             // CSR slots incl. self-loops

  const float* x = (const float*)d_in[0];
  const int* ei = (const int*)d_in[1];
  const int* e_src = ei;
  const int* e_dst = ei + E;
  const float* encW = (const float*)d_in[2];
  const float* encb = (const float*)d_in[3];
  const float* Wl[3]; const float* asl[3]; const float* adl[3]; const float* bl[3];
  const float* gl[3]; const float* bel[3]; const float* ml[3]; const float* vl[3];
  for (int l = 0; l < 3; ++l) {
    const int o = 4 + 8 * l;
    Wl[l]  = (const float*)d_in[o + 0];
    asl[l] = (const float*)d_in[o + 1];
    adl[l] = (const float*)d_in[o + 2];
    bl[l]  = (const float*)d_in[o + 3];
    gl[l]  = (const float*)d_in[o + 4];
    bel[l] = (const float*)d_in[o + 5];
    ml[l]  = (const float*)d_in[o + 6];
    vl[l]  = (const float*)d_in[o + 7];
  }
  const float* eW1 = (const float*)d_in[28];
  const float* eb1 = (const float*)d_in[29];
  const float* eW2 = (const float*)d_in[30];
  const float* eb2 = (const float*)d_in[31];
  const float* mW1 = (const float*)d_in[32];
  const float* mb1 = (const float*)d_in[33];
  const float* mW2 = (const float*)d_in[34];
  const float* mb2 = (const float*)d_in[35];

  float* out = (float*)d_out;

  // workspace layout
  float* wf = (float*)d_ws;
  size_t off = 0;
  float* hA   = wf + off; off += (size_t)N * 64;
  float* hB   = wf + off; off += (size_t)N * 64;
  unsigned short* xpb = (unsigned short*)(wf + off); off += (size_t)N * 128;  // N*256 bf16
  float* als  = wf + off; off += (size_t)N * 4;
  float* ald  = wf + off; off += (size_t)N * 4;
  float* gacc = wf + off; off += 32;
  int* wi = (int*)(wf + off);
  int* col     = wi;                     // M
  int* rbeg    = col + M;                // N
  int* rend    = rbeg + N;               // N
  int* cursor  = rend + N;               // N (deg before alloc)
  int* counter = cursor + N;             // 1

  const int T = 256;
  const int gN  = (N + T - 1) / T;
  const int gE  = (E + T - 1) / T;
  const int gGE = (N + 15) / 16;
  const int gGA = (N + 1) / 2;       // 128-thread blocks, 2 waves, 1 node/wave

  // ---- CSR build ----
  hipMemsetAsync(cursor, 0, (size_t)(N + 1) * sizeof(int), stream);  // deg + counter
  k_count<<<gE, T, 0, stream>>>(e_dst, cursor, E);
  k_alloc<<<gN, T, 0, stream>>>(cursor, rbeg, rend, col, counter, gacc, N);
  k_scatter<<<gE, T, 0, stream>>>(e_src, e_dst, cursor, col, E);

  // ---- layer 0 (encoder fused; 64 -> 64, HC=256) ----
  k_gemm_al<256, true><<<gGE, 256, 0, stream>>>(x, encW, encb, Wl[0], asl[0], adl[0],
                                                xpb, als, ald, N);
  k_gather<64, true><<<gGA, 128, 0, stream>>>(xpb, als, ald, rbeg, rend, col,
                                              bl[0], gl[0], bel[0], ml[0], vl[0], hB, N);

  // ---- layer 1 (64 -> 64, HC=256) ----
  k_gemm_al<256, false><<<gGE, 256, 0, stream>>>(hB, encW, encb, Wl[1], asl[1], adl[1],
                                                 xpb, als, ald, N);
  k_gather<64, true><<<gGA, 128, 0, stream>>>(xpb, als, ald, rbeg, rend, col,
                                              bl[1], gl[1], bel[1], ml[1], vl[1], hA, N);

  // ---- layer 2 (64 -> 32, HC=128), writes final h straight into d_out ----
  k_gemm_al<128, false><<<gGE, 128, 0, stream>>>(hA, encW, encb, Wl[2], asl[2], adl[2],
                                                 xpb, als, ald, N);
  k_gather<32, false><<<gGA, 128, 0, stream>>>(xpb, als, ald, rbeg, rend, col,
                                               bl[2], gl[2], bel[2], ml[2], vl[2], out, N);

  // ---- mean pool + heads ----
  k_reduce<<<80, 256, 0, stream>>>(out, gacc, N);
  k_heads<<<1, 64, 0, stream>>>(gacc, eW1, eb1, eW2, eb2, mW1, mb1, mW2, mb2, out, N);
}

// Round 6
// 343.535 us; speedup vs baseline: 1.9381x; 1.0357x over previous
//
#include <hip/hip_runtime.h>
#include <math.h>

// EthicalGNN: encoder -> 3x(GAT + BN (+ReLU)) -> mean-pool -> 2 MLP heads.
// R6: gather keeps 4 edges in flight (deeper MLP for the col->xp / col->als
// chains); k_heads fused into k_reduce via last-block ticket. 11 kernel
// dispatches + 1 memset.

#define H4 4  // heads

static __device__ __forceinline__ unsigned short f2bf(float f) {
  unsigned u = __float_as_uint(f);
  u += 0x7fffu + ((u >> 16) & 1u);  // round-to-nearest-even
  return (unsigned short)(u >> 16);
}

static __device__ __forceinline__ float bfh(unsigned u) {  // low bf16 -> f32
  return __uint_as_float(u << 16);
}
static __device__ __forceinline__ float bfl(unsigned u) {  // high bf16 -> f32
  return __uint_as_float(u & 0xffff0000u);
}

// ---------------- CSR build ----------------
__global__ void k_count(const int* __restrict__ dst, int* __restrict__ deg, int E) {
  int gid = blockIdx.x * blockDim.x + threadIdx.x;
  if (gid < E) atomicAdd(&deg[dst[gid]], 1);
}

// Parallel region allocator: per-wave inclusive shfl-scan of (deg+1), one
// atomicAdd per wave for the base, then per-lane offsets. Emits self-loop
// slot, initializes scatter cursor, zeroes gacc. `deg` lives in `cursor`.
__global__ void k_alloc(int* __restrict__ cursor, int* __restrict__ rbeg,
                        int* __restrict__ rend, int* __restrict__ col,
                        int* __restrict__ counter, float* __restrict__ gacc, int N) {
  int gid = blockIdx.x * blockDim.x + threadIdx.x;
  int lane = threadIdx.x & 63;
  if (gid < 32) gacc[gid] = 0.f;  // runs before k_reduce in-stream
  int size = (gid < N) ? (cursor[gid] + 1) : 0;  // +1 = self-loop
  int v = size;
#pragma unroll
  for (int off = 1; off < 64; off <<= 1) {
    int t = __shfl_up(v, off, 64);
    if (lane >= off) v += t;
  }
  int tot = __shfl(v, 63, 64);
  int base = 0;
  if (lane == 63) base = atomicAdd(counter, tot);
  base = __shfl(base, 63, 64);
  if (gid < N) {
    int p = base + v - size;  // exclusive prefix
    rbeg[gid] = p;
    rend[gid] = p + size;
    col[p] = gid;             // self-loop slot
    cursor[gid] = p + 1;
  }
}

__global__ void k_scatter(const int* __restrict__ src, const int* __restrict__ dst,
                          int* __restrict__ cursor, int* __restrict__ col, int E) {
  int gid = blockIdx.x * blockDim.x + threadIdx.x;
  if (gid < E) {
    int p = atomicAdd(&cursor[dst[gid]], 1);
    col[p] = src[gid];
  }
}

// ---------------- fused GEMM + attention logits ----------------
template <int HC, bool ENC>
__global__ void k_gemm_al(const float* __restrict__ hin,
                          const float* __restrict__ encW, const float* __restrict__ encb,
                          const float* __restrict__ W,
                          const float* __restrict__ a_s, const float* __restrict__ a_d,
                          unsigned short* __restrict__ xpb,
                          float* __restrict__ als, float* __restrict__ ald, int N) {
  constexpr int K = 64, NB = 16, C = HC / H4;
  __shared__ float hs[NB * K];
  int n0 = blockIdx.x * NB;
  int tid = threadIdx.x;  // output column
  if (ENC) {
    for (int idx = tid; idx < NB * K; idx += HC) {
      int i = idx >> 6, j = idx & 63;
      int n = n0 + i;
      float a = 0.f;
      if (n < N) {
        a = encb[j];
#pragma unroll
        for (int k = 0; k < 5; ++k) a += hin[n * 5 + k] * encW[k * 64 + j];
      }
      hs[idx] = a;
    }
  } else {
    for (int idx = tid; idx < NB * K; idx += HC) {
      int n = n0 + (idx >> 6);
      hs[idx] = (n < N) ? hin[(size_t)n0 * K + idx] : 0.f;
    }
  }
  __syncthreads();
  float acc[NB];
#pragma unroll
  for (int i = 0; i < NB; ++i) acc[i] = 0.f;
  for (int k = 0; k < K; k += 4) {
    float w0 = W[(k + 0) * HC + tid];
    float w1 = W[(k + 1) * HC + tid];
    float w2 = W[(k + 2) * HC + tid];
    float w3 = W[(k + 3) * HC + tid];
#pragma unroll
    for (int i = 0; i < NB; ++i) {
      float4 hv = *(const float4*)&hs[i * K + k];
      acc[i] += hv.x * w0 + hv.y * w1 + hv.z * w2 + hv.w * w3;
    }
  }
#pragma unroll
  for (int i = 0; i < NB; ++i) {
    int n = n0 + i;
    if (n < N) xpb[(size_t)n * HC + tid] = f2bf(acc[i]);
  }
  float as_w = a_s[tid], ad_w = a_d[tid];
  int c = tid & (C - 1);
  int h = tid / C;
#pragma unroll
  for (int i = 0; i < NB; ++i) {
    float vs = acc[i] * as_w, vd = acc[i] * ad_w;
#pragma unroll
    for (int off = C >> 1; off; off >>= 1) {
      vs += __shfl_xor(vs, off, 64);
      vd += __shfl_xor(vd, off, 64);
    }
    int n = n0 + i;
    if (c == 0 && n < N) {
      als[n * H4 + h] = vs;
      ald[n * H4 + h] = vd;
    }
  }
}

// ---------------- single-pass gather, 4 edges in flight ----------------
// lane = h*16 + c4. alpha = exp(lrelu(als[src]+ald[n])) / (sum + 1e-16).
template <int C, bool RELU>
__global__ void k_gather(const unsigned short* __restrict__ xpb,
                         const float* __restrict__ als, const float* __restrict__ ald,
                         const int* __restrict__ rbeg, const int* __restrict__ rend,
                         const int* __restrict__ col,
                         const float* __restrict__ bias, const float* __restrict__ g,
                         const float* __restrict__ be, const float* __restrict__ m,
                         const float* __restrict__ v, float* __restrict__ hout, int N) {
  constexpr int HC = H4 * C;
  constexpr int VPL = HC / 64;  // 4 (C=64) or 2 (C=32)
  int wave = threadIdx.x >> 6;
  int lane = threadIdx.x & 63;
  int n = blockIdx.x * 2 + wave;  // 128-thread blocks, 2 waves
  if (n >= N) return;
  int h = lane >> 4;
  float aldn = ald[n * H4 + h];
  int beg = rbeg[n], end = rend[n];

  float s = 0.f;
  float acc[VPL];
#pragma unroll
  for (int i = 0; i < VPL; ++i) acc[i] = 0.f;

  int j = beg;
  for (; j + 3 < end; j += 4) {  // 4 edges in flight
    int s0 = col[j], s1 = col[j + 1], s2 = col[j + 2], s3 = col[j + 3];
    float a0 = als[s0 * H4 + h], a1 = als[s1 * H4 + h];
    float a2 = als[s2 * H4 + h], a3 = als[s3 * H4 + h];
    float e0 = a0 + aldn; e0 = (e0 > 0.f) ? e0 : 0.2f * e0; e0 = __expf(e0);
    float e1 = a1 + aldn; e1 = (e1 > 0.f) ? e1 : 0.2f * e1; e1 = __expf(e1);
    float e2 = a2 + aldn; e2 = (e2 > 0.f) ? e2 : 0.2f * e2; e2 = __expf(e2);
    float e3 = a3 + aldn; e3 = (e3 > 0.f) ? e3 : 0.2f * e3; e3 = __expf(e3);
    s += (e0 + e1) + (e2 + e3);
    if constexpr (VPL == 4) {
      uint2 u0 = *(const uint2*)(xpb + (size_t)s0 * HC + lane * 4);
      uint2 u1 = *(const uint2*)(xpb + (size_t)s1 * HC + lane * 4);
      uint2 u2 = *(const uint2*)(xpb + (size_t)s2 * HC + lane * 4);
      uint2 u3 = *(const uint2*)(xpb + (size_t)s3 * HC + lane * 4);
      acc[0] += e0 * bfh(u0.x) + e1 * bfh(u1.x) + e2 * bfh(u2.x) + e3 * bfh(u3.x);
      acc[1] += e0 * bfl(u0.x) + e1 * bfl(u1.x) + e2 * bfl(u2.x) + e3 * bfl(u3.x);
      acc[2] += e0 * bfh(u0.y) + e1 * bfh(u1.y) + e2 * bfh(u2.y) + e3 * bfh(u3.y);
      acc[3] += e0 * bfl(u0.y) + e1 * bfl(u1.y) + e2 * bfl(u2.y) + e3 * bfl(u3.y);
    } else {
      unsigned u0 = *(const unsigned*)(xpb + (size_t)s0 * HC + lane * 2);
      unsigned u1 = *(const unsigned*)(xpb + (size_t)s1 * HC + lane * 2);
      unsigned u2 = *(const unsigned*)(xpb + (size_t)s2 * HC + lane * 2);
      unsigned u3 = *(const unsigned*)(xpb + (size_t)s3 * HC + lane * 2);
      acc[0] += e0 * bfh(u0) + e1 * bfh(u1) + e2 * bfh(u2) + e3 * bfh(u3);
      acc[1] += e0 * bfl(u0) + e1 * bfl(u1) + e2 * bfl(u2) + e3 * bfl(u3);
    }
  }
  for (; j < end; ++j) {  // tail
    int s0 = col[j];
    float a0 = als[s0 * H4 + h];
    float e0 = a0 + aldn; e0 = (e0 > 0.f) ? e0 : 0.2f * e0; e0 = __expf(e0);
    s += e0;
    if constexpr (VPL == 4) {
      uint2 u0 = *(const uint2*)(xpb + (size_t)s0 * HC + lane * 4);
      acc[0] += e0 * bfh(u0.x);
      acc[1] += e0 * bfl(u0.x);
      acc[2] += e0 * bfh(u0.y);
      acc[3] += e0 * bfl(u0.y);
    } else {
      unsigned u0 = *(const unsigned*)(xpb + (size_t)s0 * HC + lane * 2);
      acc[0] += e0 * bfh(u0);
      acc[1] += e0 * bfl(u0);
    }
  }

  float inv = 1.f / (s + 1e-16f);
#pragma unroll
  for (int i = 0; i < VPL; ++i) {
    acc[i] *= inv;
    acc[i] += __shfl_xor(acc[i], 16, 64);  // head sum (bits 4,5 = head)
    acc[i] += __shfl_xor(acc[i], 32, 64);
  }

  if (lane < 16) {
    int c0 = lane * VPL;
    float o[VPL];
#pragma unroll
    for (int i = 0; i < VPL; ++i) {
      int cc = c0 + i;
      float t = acc[i] * (1.f / H4) + bias[cc];
      t = (t - m[cc]) * rsqrtf(v[cc] + 1e-5f) * g[cc] + be[cc];
      if (RELU) t = fmaxf(t, 0.f);
      o[i] = t;
    }
    if constexpr (VPL == 4)
      *(float4*)&hout[(size_t)n * C + c0] = make_float4(o[0], o[1], o[2], o[3]);
    else
      *(float2*)&hout[(size_t)n * C + c0] = make_float2(o[0], o[1]);
  }
}

// ---------------- mean pool + heads (fused, last-block ticket) ----------------
__global__ void k_reduce_heads(const float* __restrict__ hfin, float* __restrict__ gacc,
                               int* __restrict__ ticket,
                               const float* __restrict__ eW1, const float* __restrict__ eb1,
                               const float* __restrict__ eW2, const float* __restrict__ eb2,
                               const float* __restrict__ mW1, const float* __restrict__ mb1,
                               const float* __restrict__ mW2, const float* __restrict__ mb2,
                               float* __restrict__ out, int N) {
  __shared__ float lds[256];
  __shared__ bool last;
  int tid = threadIdx.x;
  int c = tid & 31;
  int rowStart = blockIdx.x * (blockDim.x / 32) + (tid >> 5);
  int rowStride = gridDim.x * (blockDim.x / 32);
  float acc = 0.f;
  for (int n = rowStart; n < N; n += rowStride) acc += hfin[(size_t)n * 32 + c];
  lds[tid] = acc;
  __syncthreads();
  if (tid < 32) {
    float s = 0.f;
#pragma unroll
    for (int i = 0; i < 8; ++i) s += lds[i * 32 + tid];
    atomicAdd(&gacc[tid], s);
  }
  __threadfence();
  __syncthreads();
  if (tid == 0) last = (atomicAdd(ticket, 1) == (int)gridDim.x - 1);
  __syncthreads();
  if (!last) return;

  // final block: graph_emb + 2 MLP heads
  __shared__ float z[32];
  __shared__ float hid[32];  // [0:16) ethics, [16:32) manip
  size_t base = (size_t)N * 32;
  if (tid < 32) {
    float zv = atomicAdd(&gacc[tid], 0.f) / (float)N;  // coherent read
    z[tid] = zv;
    out[base + tid] = zv;  // graph_emb
  }
  __syncthreads();
  if (tid < 16) {
    float a = eb1[tid], b = mb1[tid];
    for (int k = 0; k < 32; ++k) {
      a += z[k] * eW1[k * 16 + tid];
      b += z[k] * mW1[k * 16 + tid];
    }
    hid[tid] = fmaxf(a, 0.f);
    hid[16 + tid] = fmaxf(b, 0.f);
  }
  __syncthreads();
  if (tid == 0) {
    float a = eb2[0];
    for (int k = 0; k < 16; ++k) a += hid[k] * eW2[k];
    out[base + 32] = 1.f / (1.f + __expf(-a));
  } else if (tid == 1) {
    float a = mb2[0];
    for (int k = 0; k < 16; ++k) a += hid[16 + k] * mW2[k];
    out[base + 33] = 1.f / (1.f + __expf(-a));
  }
}

extern "C" void kernel_launch(void* const* d_in, const int* in_sizes, int n_in,
                              void* d_out, int out_size, void* d_ws, size_t ws_size,
                              hipStream_t stream) {
  const int N = in_sizes[0] / 5;   // x is (N,5)
  const int E = in_sizes[1] / 2;   // edge_index is (2,E)
  const int M = E + N;             // CSR slots incl. self-loops

  const float* x = (const float*)d_in[0];
  const int* ei = (const int*)d_in[1];
  const int* e_src = ei;
  const int* e_dst = ei + E;
  const float* encW = (const float*)d_in[2];
  const float* encb = (const float*)d_in[3];
  const float* Wl[3]; const float* asl[3]; const float* adl[3]; const float* bl[3];
  const float* gl[3]; const float* bel[3]; const float* ml[3]; const float* vl[3];
  for (int l = 0; l < 3; ++l) {
    const int o = 4 + 8 * l;
    Wl[l]  = (const float*)d_in[o + 0];
    asl[l] = (const float*)d_in[o + 1];
    adl[l] = (const float*)d_in[o + 2];
    bl[l]  = (const float*)d_in[o + 3];
    gl[l]  = (const float*)d_in[o + 4];
    bel[l] = (const float*)d_in[o + 5];
    ml[l]  = (const float*)d_in[o + 6];
    vl[l]  = (const float*)d_in[o + 7];
  }
  const float* eW1 = (const float*)d_in[28];
  const float* eb1 = (const float*)d_in[29];
  const float* eW2 = (const float*)d_in[30];
  const float* eb2 = (const float*)d_in[31];
  const float* mW1 = (const float*)d_in[32];
  const float* mb1 = (const float*)d_in[33];
  const float* mW2 = (const float*)d_in[34];
  const float* mb2 = (const float*)d_in[35];

  float* out = (float*)d_out;

  // workspace layout
  float* wf = (float*)d_ws;
  size_t off = 0;
  float* hA   = wf + off; off += (size_t)N * 64;
  float* hB   = wf + off; off += (size_t)N * 64;
  unsigned short* xpb = (unsigned short*)(wf + off); off += (size_t)N * 128;  // N*256 bf16
  float* als  = wf + off; off += (size_t)N * 4;
  float* ald  = wf + off; off += (size_t)N * 4;
  float* gacc = wf + off; off += 32;
  int* wi = (int*)(wf + off);
  int* col     = wi;                     // M
  int* rbeg    = col + M;                // N
  int* rend    = rbeg + N;               // N
  int* cursor  = rend + N;               // N (deg before alloc)
  int* counter = cursor + N;             // 1
  int* ticket  = counter + 1;            // 1

  const int T = 256;
  const int gE  = (E + T - 1) / T;
  const int gN  = (N + T - 1) / T;
  const int gGE = (N + 15) / 16;
  const int gGA = (N + 1) / 2;       // 128-thread blocks, 2 waves, 1 node/wave

  // ---- CSR build ----
  hipMemsetAsync(cursor, 0, (size_t)(N + 2) * sizeof(int), stream);  // deg+counter+ticket
  k_count<<<gE, T, 0, stream>>>(e_dst, cursor, E);
  k_alloc<<<gN, T, 0, stream>>>(cursor, rbeg, rend, col, counter, gacc, N);
  k_scatter<<<gE, T, 0, stream>>>(e_src, e_dst, cursor, col, E);

  // ---- layer 0 (encoder fused; 64 -> 64, HC=256) ----
  k_gemm_al<256, true><<<gGE, 256, 0, stream>>>(x, encW, encb, Wl[0], asl[0], adl[0],
                                                xpb, als, ald, N);
  k_gather<64, true><<<gGA, 128, 0, stream>>>(xpb, als, ald, rbeg, rend, col,
                                              bl[0], gl[0], bel[0], ml[0], vl[0], hB, N);

  // ---- layer 1 (64 -> 64, HC=256) ----
  k_gemm_al<256, false><<<gGE, 256, 0, stream>>>(hB, encW, encb, Wl[1], asl[1], adl[1],
                                                 xpb, als, ald, N);
  k_gather<64, true><<<gGA, 128, 0, stream>>>(xpb, als, ald, rbeg, rend, col,
                                              bl[1], gl[1], bel[1], ml[1], vl[1], hA, N);

  // ---- layer 2 (64 -> 32, HC=128), writes final h straight into d_out ----
  k_gemm_al<128, false><<<gGE, 128, 0, stream>>>(hA, encW, encb, Wl[2], asl[2], adl[2],
                                                 xpb, als, ald, N);
  k_gather<32, false><<<gGA, 128, 0, stream>>>(xpb, als, ald, rbeg, rend, col,
                                               bl[2], gl[2], bel[2], ml[2], vl[2], out, N);

  // ---- mean pool + heads (fused) ----
  k_reduce_heads<<<80, 256, 0, stream>>>(out, gacc, ticket,
                                         eW1, eb1, eW2, eb2, mW1, mb1, mW2, mb2, out, N);
}

// Round 7
// 332.896 us; speedup vs baseline: 2.0001x; 1.0320x over previous
//
#include <hip/hip_runtime.h>
#include <math.h>

// EthicalGNN: encoder -> 3x(GAT + BN (+ReLU)) -> mean-pool -> 2 MLP heads.
// R7: gather uses 2 waves/node (split edge range + LDS combine) for 2x memory
// parallelism; GEMM logits via precomputed was/wad = W@a (k_alloc blocks 0-2)
// instead of shfl butterflies; mean-pool folded into gather2 via bucketed
// atomics + 1-block k_heads2. 10 kernels + 1 memset.

#define H4 4  // heads

static __device__ __forceinline__ unsigned short f2bf(float f) {
  unsigned u = __float_as_uint(f);
  u += 0x7fffu + ((u >> 16) & 1u);  // round-to-nearest-even
  return (unsigned short)(u >> 16);
}

static __device__ __forceinline__ float bfh(unsigned u) {  // low bf16 -> f32
  return __uint_as_float(u << 16);
}
static __device__ __forceinline__ float bfl(unsigned u) {  // high bf16 -> f32
  return __uint_as_float(u & 0xffff0000u);
}

// ---------------- CSR build ----------------
__global__ void k_count(const int* __restrict__ dst, int* __restrict__ deg, int E) {
  int gid = blockIdx.x * blockDim.x + threadIdx.x;
  if (gid < E) atomicAdd(&deg[dst[gid]], 1);
}

// Parallel region allocator (wave shfl-scan + one atomicAdd per wave).
// Blocks 0..2 additionally precompute was/wad[k,h] = sum_c W[k,h*C+c]*a[h,c]
// for layer = blockIdx.x (reassociated attention logits).
__global__ void k_alloc(int* __restrict__ cursor, int* __restrict__ rbeg,
                        int* __restrict__ rend, int* __restrict__ col,
                        int* __restrict__ counter, int N,
                        const float* __restrict__ W0, const float* __restrict__ as0, const float* __restrict__ ad0,
                        const float* __restrict__ W1, const float* __restrict__ as1, const float* __restrict__ ad1,
                        const float* __restrict__ W2, const float* __restrict__ as2, const float* __restrict__ ad2,
                        float* __restrict__ pas, float* __restrict__ pad) {
  int gid = blockIdx.x * blockDim.x + threadIdx.x;
  int lane = threadIdx.x & 63;
  int size = (gid < N) ? (cursor[gid] + 1) : 0;  // +1 = self-loop
  int v = size;
#pragma unroll
  for (int off = 1; off < 64; off <<= 1) {
    int t = __shfl_up(v, off, 64);
    if (lane >= off) v += t;
  }
  int tot = __shfl(v, 63, 64);
  int base = 0;
  if (lane == 63) base = atomicAdd(counter, tot);
  base = __shfl(base, 63, 64);
  if (gid < N) {
    int p = base + v - size;  // exclusive prefix
    rbeg[gid] = p;
    rend[gid] = p + size;
    col[p] = gid;             // self-loop slot
    cursor[gid] = p + 1;
  }
  // logit-projection prep (one layer per block, threads = (k,h) pairs)
  if (blockIdx.x < 3) {
    int l = blockIdx.x;
    const float* W  = (l == 0) ? W0 : (l == 1) ? W1 : W2;
    const float* ap = (l == 0) ? as0 : (l == 1) ? as1 : as2;
    const float* dp = (l == 0) ? ad0 : (l == 1) ? ad1 : ad2;
    int HC = (l == 2) ? 128 : 256;
    int C  = HC / H4;
    int tid = threadIdx.x;  // k*4 + h
    int k = tid >> 2, h = tid & 3;
    float vs = 0.f, vd = 0.f;
    for (int c = 0; c < C; ++c) {
      float w = W[k * HC + h * C + c];
      vs += w * ap[h * C + c];
      vd += w * dp[h * C + c];
    }
    pas[l * 256 + tid] = vs;
    pad[l * 256 + tid] = vd;
  }
}

__global__ void k_scatter(const int* __restrict__ src, const int* __restrict__ dst,
                          int* __restrict__ cursor, int* __restrict__ col, int E) {
  int gid = blockIdx.x * blockDim.x + threadIdx.x;
  if (gid < E) {
    int p = atomicAdd(&cursor[dst[gid]], 1);
    col[p] = src[gid];
  }
}

// ---------------- fused GEMM + attention logits ----------------
// xp(bf16) = hin @ W ; als/ald = hin @ was/wad (64 threads, from LDS hs).
template <int HC, bool ENC>
__global__ void k_gemm_al(const float* __restrict__ hin,
                          const float* __restrict__ encW, const float* __restrict__ encb,
                          const float* __restrict__ W,
                          const float* __restrict__ was, const float* __restrict__ wad,
                          unsigned short* __restrict__ xpb,
                          float* __restrict__ als, float* __restrict__ ald, int N) {
  constexpr int K = 64, NB = 16;
  __shared__ float hs[NB * K];
  int n0 = blockIdx.x * NB;
  int tid = threadIdx.x;  // output column
  if (ENC) {
    for (int idx = tid; idx < NB * K; idx += HC) {
      int i = idx >> 6, j = idx & 63;
      int n = n0 + i;
      float a = 0.f;
      if (n < N) {
        a = encb[j];
#pragma unroll
        for (int k = 0; k < 5; ++k) a += hin[n * 5 + k] * encW[k * 64 + j];
      }
      hs[idx] = a;
    }
  } else {
    for (int idx = tid; idx < NB * K; idx += HC) {
      int n = n0 + (idx >> 6);
      hs[idx] = (n < N) ? hin[(size_t)n0 * K + idx] : 0.f;
    }
  }
  __syncthreads();
  float acc[NB];
#pragma unroll
  for (int i = 0; i < NB; ++i) acc[i] = 0.f;
  for (int k = 0; k < K; k += 4) {
    float w0 = W[(k + 0) * HC + tid];
    float w1 = W[(k + 1) * HC + tid];
    float w2 = W[(k + 2) * HC + tid];
    float w3 = W[(k + 3) * HC + tid];
#pragma unroll
    for (int i = 0; i < NB; ++i) {
      float4 hv = *(const float4*)&hs[i * K + k];
      acc[i] += hv.x * w0 + hv.y * w1 + hv.z * w2 + hv.w * w3;
    }
  }
#pragma unroll
  for (int i = 0; i < NB; ++i) {
    int n = n0 + i;
    if (n < N) xpb[(size_t)n * HC + tid] = f2bf(acc[i]);
  }
  // logits: 64 threads cover (node i, head h) pairs; dot from LDS
  if (tid < NB * H4) {
    int i = tid >> 2, h = tid & 3;
    int n = n0 + i;
    float vs = 0.f, vd = 0.f;
#pragma unroll 8
    for (int k = 0; k < K; ++k) {
      float hv = hs[i * K + k];
      vs += hv * was[k * 4 + h];
      vd += hv * wad[k * 4 + h];
    }
    if (n < N) {
      als[n * H4 + h] = vs;
      ald[n * H4 + h] = vd;
    }
  }
}

// ---------------- gather: 2 waves per node, split edge range ----------------
// lane = h*16 + c4. alpha = exp(lrelu(als[src]+ald[n])) / (sum + 1e-16).
template <int C, bool RELU, bool POOL>
__global__ __launch_bounds__(128) void k_gather(
    const unsigned short* __restrict__ xpb,
    const float* __restrict__ als, const float* __restrict__ ald,
    const int* __restrict__ rbeg, const int* __restrict__ rend,
    const int* __restrict__ col,
    const float* __restrict__ bias, const float* __restrict__ g,
    const float* __restrict__ be, const float* __restrict__ m,
    const float* __restrict__ v, float* __restrict__ hout,
    float* __restrict__ gpart, int N) {
  constexpr int HC = H4 * C;
  constexpr int VPL = HC / 64;  // 4 (C=64) or 2 (C=32)
  __shared__ float accbuf[HC];
  __shared__ float sbuf[H4];
  int sub = threadIdx.x >> 6;   // 0 or 1
  int lane = threadIdx.x & 63;
  int n = blockIdx.x;
  int h = lane >> 4;
  float aldn = ald[n * H4 + h];
  int beg = rbeg[n], end = rend[n];
  int len = end - beg;
  int lenA = (len + 1) >> 1;
  int jb = sub ? (beg + lenA) : beg;
  int je = sub ? end : (beg + lenA);

  float s = 0.f;
  float acc[VPL];
#pragma unroll
  for (int i = 0; i < VPL; ++i) acc[i] = 0.f;

  int j = jb;
  for (; j + 3 < je; j += 4) {  // 4 edges in flight per wave
    int s0 = col[j], s1 = col[j + 1], s2 = col[j + 2], s3 = col[j + 3];
    float a0 = als[s0 * H4 + h], a1 = als[s1 * H4 + h];
    float a2 = als[s2 * H4 + h], a3 = als[s3 * H4 + h];
    float e0 = a0 + aldn; e0 = (e0 > 0.f) ? e0 : 0.2f * e0; e0 = __expf(e0);
    float e1 = a1 + aldn; e1 = (e1 > 0.f) ? e1 : 0.2f * e1; e1 = __expf(e1);
    float e2 = a2 + aldn; e2 = (e2 > 0.f) ? e2 : 0.2f * e2; e2 = __expf(e2);
    float e3 = a3 + aldn; e3 = (e3 > 0.f) ? e3 : 0.2f * e3; e3 = __expf(e3);
    s += (e0 + e1) + (e2 + e3);
    if constexpr (VPL == 4) {
      uint2 u0 = *(const uint2*)(xpb + (size_t)s0 * HC + lane * 4);
      uint2 u1 = *(const uint2*)(xpb + (size_t)s1 * HC + lane * 4);
      uint2 u2 = *(const uint2*)(xpb + (size_t)s2 * HC + lane * 4);
      uint2 u3 = *(const uint2*)(xpb + (size_t)s3 * HC + lane * 4);
      acc[0] += e0 * bfh(u0.x) + e1 * bfh(u1.x) + e2 * bfh(u2.x) + e3 * bfh(u3.x);
      acc[1] += e0 * bfl(u0.x) + e1 * bfl(u1.x) + e2 * bfl(u2.x) + e3 * bfl(u3.x);
      acc[2] += e0 * bfh(u0.y) + e1 * bfh(u1.y) + e2 * bfh(u2.y) + e3 * bfh(u3.y);
      acc[3] += e0 * bfl(u0.y) + e1 * bfl(u1.y) + e2 * bfl(u2.y) + e3 * bfl(u3.y);
    } else {
      unsigned u0 = *(const unsigned*)(xpb + (size_t)s0 * HC + lane * 2);
      unsigned u1 = *(const unsigned*)(xpb + (size_t)s1 * HC + lane * 2);
      unsigned u2 = *(const unsigned*)(xpb + (size_t)s2 * HC + lane * 2);
      unsigned u3 = *(const unsigned*)(xpb + (size_t)s3 * HC + lane * 2);
      acc[0] += e0 * bfh(u0) + e1 * bfh(u1) + e2 * bfh(u2) + e3 * bfh(u3);
      acc[1] += e0 * bfl(u0) + e1 * bfl(u1) + e2 * bfl(u2) + e3 * bfl(u3);
    }
  }
  for (; j < je; ++j) {  // tail
    int s0 = col[j];
    float a0 = als[s0 * H4 + h];
    float e0 = a0 + aldn; e0 = (e0 > 0.f) ? e0 : 0.2f * e0; e0 = __expf(e0);
    s += e0;
    if constexpr (VPL == 4) {
      uint2 u0 = *(const uint2*)(xpb + (size_t)s0 * HC + lane * 4);
      acc[0] += e0 * bfh(u0.x);
      acc[1] += e0 * bfl(u0.x);
      acc[2] += e0 * bfh(u0.y);
      acc[3] += e0 * bfl(u0.y);
    } else {
      unsigned u0 = *(const unsigned*)(xpb + (size_t)s0 * HC + lane * 2);
      acc[0] += e0 * bfh(u0);
      acc[1] += e0 * bfl(u0);
    }
  }

  // combine wave1 -> wave0
  if (sub) {
    if ((lane & 15) == 0) sbuf[h] = s;
#pragma unroll
    for (int i = 0; i < VPL; ++i) accbuf[lane * VPL + i] = acc[i];
  }
  __syncthreads();
  if (sub) return;
  s += sbuf[h];
#pragma unroll
  for (int i = 0; i < VPL; ++i) acc[i] += accbuf[lane * VPL + i];

  float inv = 1.f / (s + 1e-16f);
#pragma unroll
  for (int i = 0; i < VPL; ++i) {
    acc[i] *= inv;
    acc[i] += __shfl_xor(acc[i], 16, 64);  // head sum (bits 4,5 = head)
    acc[i] += __shfl_xor(acc[i], 32, 64);
  }

  if (lane < 16) {
    int c0 = lane * VPL;
    float o[VPL];
#pragma unroll
    for (int i = 0; i < VPL; ++i) {
      int cc = c0 + i;
      float t = acc[i] * (1.f / H4) + bias[cc];
      t = (t - m[cc]) * rsqrtf(v[cc] + 1e-5f) * g[cc] + be[cc];
      if (RELU) t = fmaxf(t, 0.f);
      o[i] = t;
      if (POOL) atomicAdd(&gpart[(blockIdx.x & 255) * 32 + cc], t);
    }
    if constexpr (VPL == 4)
      *(float4*)&hout[(size_t)n * C + c0] = make_float4(o[0], o[1], o[2], o[3]);
    else
      *(float2*)&hout[(size_t)n * C + c0] = make_float2(o[0], o[1]);
  }
}

// ---------------- graph_emb + 2 MLP heads (reads bucketed partials) ----------------
__global__ void k_heads2(const float* __restrict__ gpart,
                         const float* __restrict__ eW1, const float* __restrict__ eb1,
                         const float* __restrict__ eW2, const float* __restrict__ eb2,
                         const float* __restrict__ mW1, const float* __restrict__ mb1,
                         const float* __restrict__ mW2, const float* __restrict__ mb2,
                         float* __restrict__ out, int N) {
  __shared__ float red[256];
  __shared__ float z[32];
  __shared__ float hid[32];  // [0:16) ethics, [16:32) manip
  int tid = threadIdx.x;
  int c = tid & 31;
  float s = 0.f;
  for (int b = tid >> 5; b < 256; b += 8) s += gpart[b * 32 + c];
  red[tid] = s;
  __syncthreads();
  size_t base = (size_t)N * 32;
  if (tid < 32) {
    float t = 0.f;
#pragma unroll
    for (int i = 0; i < 8; ++i) t += red[i * 32 + tid];
    t /= (float)N;
    z[tid] = t;
    out[base + tid] = t;  // graph_emb
  }
  __syncthreads();
  if (tid < 16) {
    float a = eb1[tid], b = mb1[tid];
    for (int k = 0; k < 32; ++k) {
      a += z[k] * eW1[k * 16 + tid];
      b += z[k] * mW1[k * 16 + tid];
    }
    hid[tid] = fmaxf(a, 0.f);
    hid[16 + tid] = fmaxf(b, 0.f);
  }
  __syncthreads();
  if (tid == 0) {
    float a = eb2[0];
    for (int k = 0; k < 16; ++k) a += hid[k] * eW2[k];
    out[base + 32] = 1.f / (1.f + __expf(-a));
  } else if (tid == 1) {
    float a = mb2[0];
    for (int k = 0; k < 16; ++k) a += hid[16 + k] * mW2[k];
    out[base + 33] = 1.f / (1.f + __expf(-a));
  }
}

extern "C" void kernel_launch(void* const* d_in, const int* in_sizes, int n_in,
                              void* d_out, int out_size, void* d_ws, size_t ws_size,
                              hipStream_t stream) {
  const int N = in_sizes[0] / 5;   // x is (N,5)
  const int E = in_sizes[1] / 2;   // edge_index is (2,E)
  const int M = E + N;             // CSR slots incl. self-loops

  const float* x = (const float*)d_in[0];
  const int* ei = (const int*)d_in[1];
  const int* e_src = ei;
  const int* e_dst = ei + E;
  const float* encW = (const float*)d_in[2];
  const float* encb = (const float*)d_in[3];
  const float* Wl[3]; const float* asl[3]; const float* adl[3]; const float* bl[3];
  const float* gl[3]; const float* bel[3]; const float* ml[3]; const float* vl[3];
  for (int l = 0; l < 3; ++l) {
    const int o = 4 + 8 * l;
    Wl[l]  = (const float*)d_in[o + 0];
    asl[l] = (const float*)d_in[o + 1];
    adl[l] = (const float*)d_in[o + 2];
    bl[l]  = (const float*)d_in[o + 3];
    gl[l]  = (const float*)d_in[o + 4];
    bel[l] = (const float*)d_in[o + 5];
    ml[l]  = (const float*)d_in[o + 6];
    vl[l]  = (const float*)d_in[o + 7];
  }
  const float* eW1 = (const float*)d_in[28];
  const float* eb1 = (const float*)d_in[29];
  const float* eW2 = (const float*)d_in[30];
  const float* eb2 = (const float*)d_in[31];
  const float* mW1 = (const float*)d_in[32];
  const float* mb1 = (const float*)d_in[33];
  const float* mW2 = (const float*)d_in[34];
  const float* mb2 = (const float*)d_in[35];

  float* out = (float*)d_out;

  // workspace layout: floats, then int region, then gpart (memset w/ cursor)
  float* wf = (float*)d_ws;
  size_t off = 0;
  float* hA   = wf + off; off += (size_t)N * 64;
  float* hB   = wf + off; off += (size_t)N * 64;
  unsigned short* xpb = (unsigned short*)(wf + off); off += (size_t)N * 128;  // N*256 bf16
  float* als  = wf + off; off += (size_t)N * 4;
  float* ald  = wf + off; off += (size_t)N * 4;
  float* pas  = wf + off; off += 3 * 256;
  float* pad  = wf + off; off += 3 * 256;
  int* wi = (int*)(wf + off);
  int* col     = wi;                     // M
  int* rbeg    = col + M;                // N
  int* rend    = rbeg + N;               // N
  int* cursor  = rend + N;               // N (deg before alloc)  } zeroed by
  int* counter = cursor + N;             // 1                     } one memset
  float* gpart = (float*)(counter + 1);  // 256*32                } (contiguous)

  const int T = 256;
  const int gE  = (E + T - 1) / T;
  const int gN  = (N + T - 1) / T;
  const int gGE = (N + 15) / 16;

  // ---- CSR build (memset covers cursor, counter, gpart) ----
  hipMemsetAsync(cursor, 0, (size_t)(N + 1) * sizeof(int) + 256 * 32 * sizeof(float), stream);
  k_count<<<gE, T, 0, stream>>>(e_dst, cursor, E);
  k_alloc<<<gN, T, 0, stream>>>(cursor, rbeg, rend, col, counter, N,
                                Wl[0], asl[0], adl[0], Wl[1], asl[1], adl[1],
                                Wl[2], asl[2], adl[2], pas, pad);
  k_scatter<<<gE, T, 0, stream>>>(e_src, e_dst, cursor, col, E);

  // ---- layer 0 (encoder fused; 64 -> 64, HC=256) ----
  k_gemm_al<256, true><<<gGE, 256, 0, stream>>>(x, encW, encb, Wl[0], pas, pad,
                                                xpb, als, ald, N);
  k_gather<64, true, false><<<N, 128, 0, stream>>>(xpb, als, ald, rbeg, rend, col,
                                                   bl[0], gl[0], bel[0], ml[0], vl[0],
                                                   hB, gpart, N);

  // ---- layer 1 (64 -> 64, HC=256) ----
  k_gemm_al<256, false><<<gGE, 256, 0, stream>>>(hB, encW, encb, Wl[1], pas + 256, pad + 256,
                                                 xpb, als, ald, N);
  k_gather<64, true, false><<<N, 128, 0, stream>>>(xpb, als, ald, rbeg, rend, col,
                                                   bl[1], gl[1], bel[1], ml[1], vl[1],
                                                   hA, gpart, N);

  // ---- layer 2 (64 -> 32, HC=128), writes final h into d_out + pooled buckets ----
  k_gemm_al<128, false><<<gGE, 128, 0, stream>>>(hA, encW, encb, Wl[2], pas + 512, pad + 512,
                                                 xpb, als, ald, N);
  k_gather<32, false, true><<<N, 128, 0, stream>>>(xpb, als, ald, rbeg, rend, col,
                                                   bl[2], gl[2], bel[2], ml[2], vl[2],
                                                   out, gpart, N);

  // ---- heads ----
  k_heads2<<<1, 256, 0, stream>>>(gpart, eW1, eb1, eW2, eb2, mW1, mb1, mW2, mb2, out, N);
}